// Round 6
// baseline (195.039 us; speedup 1.0000x reference)
//
#include <hip/hip_runtime.h>
#include <hip/hip_bf16.h>

typedef unsigned short u16;

#define B_    4
#define T_    4096
#define C_    512
#define H_    8
#define D_    64
#define WIN_  15
#define PAD_  7
#define M_    (B_*T_)      // 16384 rows
#define NQKV  1536
#define KDIM  512

typedef __bf16 bf16x8 __attribute__((ext_vector_type(8)));
typedef float  f32x4  __attribute__((ext_vector_type(4)));

__device__ __forceinline__ u16 f2bf(float f) {
    union { float f; unsigned int i; } c; c.f = f;
    unsigned int lsb = (c.i >> 16) & 1u;
    c.i += 0x7fffu + lsb;                 // round-to-nearest-even
    return (u16)(c.i >> 16);
}
__device__ __forceinline__ float bf2f(u16 u) {
    union { unsigned int i; float f; } c; c.i = ((unsigned int)u) << 16; return c.f;
}

// BK=32 swizzle for the 128^2 kernel (unchanged, verified R9).
__device__ __forceinline__ int swz(int row, int sub) {
    return (row * 4 + (sub ^ ((row >> 1) & 3))) * 8;
}

// global->LDS direct DMA, 16B per lane, dest = wave-uniform base + lane*16
__device__ __forceinline__ void gll16(const void* g, void* l) {
    __builtin_amdgcn_global_load_lds(
        (const __attribute__((address_space(1))) void*)g,
        (__attribute__((address_space(3))) void*)l, 16, 0, 0);
}

// ---------------------------------------------------------------------------
// R15: coalesced weight pack via LDS 64x64 tile transpose. (verified)
// ---------------------------------------------------------------------------
__global__ __launch_bounds__(256) void pack_weights_t(
    const float* __restrict__ Wq, const float* __restrict__ Wkv,
    const float* __restrict__ Wp,
    u16* __restrict__ Wt_qkv, u16* __restrict__ Wpt)
{
    __shared__ float tile[64][65];
    const int bid = blockIdx.x;
    const float* src; int srcld; u16* dst; int n0, k0;
    if (bid < 192) {            // Wt_qkv: n0 in [0,1536), k0 in [0,512)
        n0 = (bid % 24) * 64; k0 = (bid / 24) * 64;
        dst = Wt_qkv;
        if (n0 < 512) { src = Wq + n0;          srcld = 512;  }
        else          { src = Wkv + (n0 - 512); srcld = 1024; }
    } else {                    // Wpt
        const int b2 = bid - 192;
        n0 = (b2 % 8) * 64; k0 = (b2 / 8) * 64;
        dst = Wpt; src = Wp + n0; srcld = 512;
    }
    const int tr = threadIdx.x >> 6;   // 0..3
    const int tc = threadIdx.x & 63;
    #pragma unroll
    for (int p = 0; p < 16; p++) {
        const int kk = p * 4 + tr;
        tile[kk][tc] = src[(size_t)(k0 + kk) * srcld + tc];
    }
    __syncthreads();
    #pragma unroll
    for (int p = 0; p < 16; p++) {
        const int nn = p * 4 + tr;
        dst[(size_t)(n0 + nn) * 512 + k0 + tc] = f2bf(tile[tc][nn]);
    }
}

// ---------------------------------------------------------------------------
// xm = bf16( x_fp32 * mask[row] ) — one-time pass so GEMM1 never re-converts.
// ---------------------------------------------------------------------------
__global__ void apply_mask(const float* __restrict__ x, const float* __restrict__ mask,
                           u16* __restrict__ xm)
{
    int idx = blockIdx.x * blockDim.x + threadIdx.x;   // one per 8 elems
    int e0 = idx * 8;
    float mval = mask[e0 >> 9];
    float4 a = *(const float4*)(x + e0);
    float4 b = *(const float4*)(x + e0 + 4);
    union { uint4 u; u16 s[8]; } o;
    o.s[0] = f2bf(a.x * mval); o.s[1] = f2bf(a.y * mval);
    o.s[2] = f2bf(a.z * mval); o.s[3] = f2bf(a.w * mval);
    o.s[4] = f2bf(b.x * mval); o.s[5] = f2bf(b.y * mval);
    o.s[6] = f2bf(b.z * mval); o.s[7] = f2bf(b.w * mval);
    *(uint4*)(xm + e0) = o.u;
}

// ---------------------------------------------------------------------------
// R17 GEMM1: 256x256 tile, 8 waves (2Mx4N), BK=64, 2 LDS dbufs (128 KB),
// 4 fine phases per K-tile (T3), quarter-granular stage ledger (T4),
// setprio around MFMA clusters (T5). K = 512 = 8 K-tiles, fully unrolled.
//
// LDS layout per dbuf: A 256rows x 64K as chunks (row*8+s)*8 u16, where
// slot s holds source k-subchunk s^(row&7) (involution; read at
// s=(kh*4+quad)^(row&7) -> 2-way bank spread = free). Quarter q = rows
// q*64..q*64+63 = 8KB = one gll per wave (wave w covers rows q*64+w*8..+7).
//
// Phase order per tile: ph1(Rlo,Clo) ph2(Rlo,Chi) ph3(Rhi,Chi) ph4(Rhi,Clo).
// Register reuse: A read at ph1/ph3 (8 ds_read), B-lo at ph1/ph4, B-hi at
// ph2 (4 ds_read each) -> <=12 reads ph1, <=4 after.
// Stage stream (2-4 gll/phase/wave, 8 per tile):
//   ph1: B q0,q1 of t+1 -> other dbuf (free since (t-1).ph4)
//   ph2: B q2,q3 of t+1 -> other dbuf; then A q0,q2 of t+2 -> own dbuf
//        (A-lo last ds_read at ph1; ph2+ reads A from registers)
//   ph4: A q1,q3 of t+2 -> own dbuf (A-hi last ds_read at ph3)
// Ledger: end-of-tile s_waitcnt vmcnt(4) leaves exactly {A-lo,A-hi of t+2}
// -> tile t+1 fully landed before its first read. Never 0 until t=6 (tail).
// WAR safety: each phase's lgkmcnt(0) + closing barrier => all ds_reads of
// phase p complete before any wave issues phase p+1 stages.
// Prologue: tile0 (8 gll) + tile1 A (4 gll), vmcnt(4), barrier.
// MFMA as mfma(b, a, acc): lane&15 -> C row, quad*4+reg -> C col [R9].
// ---------------------------------------------------------------------------
__global__ __launch_bounds__(512, 2) void gemm1_256(
    const u16* __restrict__ A,        // xm, 16384x512
    const u16* __restrict__ Bt,       // Wt_qkv, 1536x512
    const float* __restrict__ bq, const float* __restrict__ bkv,
    u16* __restrict__ Cc)             // qkv 16384x1536
{
    __shared__ __align__(16) u16 As0[256 * 64];   // 32 KB each
    __shared__ __align__(16) u16 As1[256 * 64];
    __shared__ __align__(16) u16 Bs0[256 * 64];
    __shared__ __align__(16) u16 Bs1[256 * 64];

    const int tid  = threadIdx.x;
    const int wave = tid >> 6;
    const int lane = tid & 63;
    const int quad = lane >> 4;
    const int l16  = lane & 15;
    const int row0 = blockIdx.x * 256;
    const int col0 = blockIdx.y * 256;
    const int wm = (wave >> 2) * 128;  // wave rows (2 groups)
    const int wn = (wave & 3) * 64;    // wave cols (4 groups)

    f32x4 acc[8][4] = {};              // [row-group][col-group]
    bf16x8 aR[4][2], bL[2][2], bH[2][2];

    // staging address (per thread): quarter chunk c = tid -> row tid>>3,
    // slot tid&7 holds source sub (tid&7)^(row&7)
    const int rowi = tid >> 3;                 // 0..63 within quarter
    const int subx = (tid & 7) ^ (rowi & 7);
    const u16* Ag = A  + (size_t)(row0 + rowi) * 512 + subx * 8;
    const u16* Bg = Bt + (size_t)(col0 + rowi) * 512 + subx * 8;
    const int so = wave * 512;                 // wave's 1KB inside a quarter

    // fragment read offsets (u16 units)
    const int abase = (wm + l16) * 64;
    const int bbase = (wn + l16) * 64;
    const int sk0 = ((0 + quad) ^ (l16 & 7)) * 8;   // kh=0
    const int sk1 = ((4 + quad) ^ (l16 & 7)) * 8;   // kh=1

#define SGA(BUF, q, kt) gll16(Ag + (q) * 64 * 512 + (kt) * 64, &BUF[(q) * 4096 + so])
#define SGB(BUF, q, kt) gll16(Bg + (q) * 64 * 512 + (kt) * 64, &BUF[(q) * 4096 + so])

#define RD_A(BUF, RH) do { _Pragma("unroll")                                  \
    for (int rg = 0; rg < 4; rg++) {                                          \
      aR[rg][0] = *(const bf16x8*)&BUF[abase + ((RH)*64 + rg*16)*64 + sk0];   \
      aR[rg][1] = *(const bf16x8*)&BUF[abase + ((RH)*64 + rg*16)*64 + sk1];   \
    } } while (0)
#define RD_B(BUF, CL, BB) do { _Pragma("unroll")                              \
    for (int cg = 0; cg < 2; cg++) {                                          \
      BB[cg][0] = *(const bf16x8*)&BUF[bbase + ((CL)*32 + cg*16)*64 + sk0];   \
      BB[cg][1] = *(const bf16x8*)&BUF[bbase + ((CL)*32 + cg*16)*64 + sk1];   \
    } } while (0)
#define MM(RH, CL, BB) do { _Pragma("unroll")                                 \
    for (int rg = 0; rg < 4; rg++) _Pragma("unroll")                          \
      for (int cg = 0; cg < 2; cg++) {                                        \
        acc[(RH)*4+rg][(CL)*2+cg] = __builtin_amdgcn_mfma_f32_16x16x32_bf16(  \
            BB[cg][0], aR[rg][0], acc[(RH)*4+rg][(CL)*2+cg], 0, 0, 0);        \
        acc[(RH)*4+rg][(CL)*2+cg] = __builtin_amdgcn_mfma_f32_16x16x32_bf16(  \
            BB[cg][1], aR[rg][1], acc[(RH)*4+rg][(CL)*2+cg], 0, 0, 0);        \
      } } while (0)

#define BAR __builtin_amdgcn_s_barrier()
#define LGK0 do { asm volatile("s_waitcnt lgkmcnt(0)" ::: "memory");          \
                  __builtin_amdgcn_sched_barrier(0); } while (0)
#define PRIO_MM(RH, CL, BB) do { __builtin_amdgcn_s_setprio(1);               \
    MM(RH, CL, BB); __builtin_amdgcn_s_setprio(0); } while (0)

// One K-tile: RA/RB = this tile's dbuf; OBUF = other dbuf's B array.
// D1: stage B of T+1; D2/D4: stage A of T+2; WK: end-of-tile vmcnt stmt.
#define TILE(RA, RB, OBUF, T, D1, D2, WK) do {                                \
    /* ph1: rows-lo cols-lo */                                                \
    RD_A(RA, 0); RD_B(RB, 0, bL);                                             \
    if (D1) { SGB(OBUF, 0, (T)+1); SGB(OBUF, 1, (T)+1); }                     \
    BAR; LGK0; PRIO_MM(0, 0, bL); BAR;                                        \
    /* ph2: rows-lo cols-hi */                                                \
    RD_B(RB, 1, bH);                                                          \
    if (D1) { SGB(OBUF, 2, (T)+1); SGB(OBUF, 3, (T)+1); }                     \
    if (D2) { SGA(RA, 0, (T)+2); SGA(RA, 2, (T)+2); }                         \
    BAR; LGK0; PRIO_MM(0, 1, bH); BAR;                                        \
    /* ph3: rows-hi cols-hi */                                                \
    RD_A(RA, 1);                                                              \
    BAR; LGK0; PRIO_MM(1, 1, bH); BAR;                                        \
    /* ph4: rows-hi cols-lo */                                                \
    RD_B(RB, 0, bL);                                                          \
    if (D2) { SGA(RA, 1, (T)+2); SGA(RA, 3, (T)+2); }                         \
    BAR; LGK0; PRIO_MM(1, 0, bL);                                             \
    WK; BAR;                                                                  \
} while (0)

#define VMC4 asm volatile("s_waitcnt vmcnt(4)" ::: "memory")
#define VMC0 asm volatile("s_waitcnt vmcnt(0)" ::: "memory")

    // prologue: tile0 full (8 gll) + tile1 A-quarters (4 gll); tile0 landed
    SGA(As0, 0, 0); SGA(As0, 1, 0); SGA(As0, 2, 0); SGA(As0, 3, 0);
    SGB(Bs0, 0, 0); SGB(Bs0, 1, 0); SGB(Bs0, 2, 0); SGB(Bs0, 3, 0);
    SGA(As1, 0, 1); SGA(As1, 1, 1); SGA(As1, 2, 1); SGA(As1, 3, 1);
    VMC4; BAR;

    TILE(As0, Bs0, Bs1, 0, true,  true,  VMC4);
    TILE(As1, Bs1, Bs0, 1, true,  true,  VMC4);
    TILE(As0, Bs0, Bs1, 2, true,  true,  VMC4);
    TILE(As1, Bs1, Bs0, 3, true,  true,  VMC4);
    TILE(As0, Bs0, Bs1, 4, true,  true,  VMC4);
    TILE(As1, Bs1, Bs0, 5, true,  true,  VMC4);
    TILE(As0, Bs0, Bs1, 6, true,  false, VMC0);
    TILE(As1, Bs1, Bs0, 7, false, false, (void)0);

#undef TILE
#undef VMC4
#undef VMC0

    // epilogue: bias add, bf16 pack, register-direct uint2 stores
    #pragma unroll
    for (int RH = 0; RH < 2; RH++)
      #pragma unroll
      for (int rg = 0; rg < 4; rg++) {
        const int row = row0 + wm + RH * 64 + rg * 16 + l16;
        #pragma unroll
        for (int CL = 0; CL < 2; CL++)
          #pragma unroll
          for (int cg = 0; cg < 2; cg++) {
            const int colb = col0 + wn + CL * 32 + cg * 16 + quad * 4;
            float4 bv = (colb < 512) ? *(const float4*)(bq + colb)
                                     : *(const float4*)(bkv + colb - 512);
            f32x4 v = acc[RH * 4 + rg][CL * 2 + cg];
            union { uint2 u; u16 s[4]; } o;
            o.s[0] = f2bf(v[0] + bv.x); o.s[1] = f2bf(v[1] + bv.y);
            o.s[2] = f2bf(v[2] + bv.z); o.s[3] = f2bf(v[3] + bv.w);
            *(uint2*)(Cc + (size_t)row * NQKV + colb) = o.u;
          }
      }
}

// ---------------------------------------------------------------------------
// R16 GEMM (kept for GEMM2 only): 128x128, 4 waves, triple-buffer counted-
// vmcnt ledger, one s_barrier per K-step. GEMM2's N=512 -> only 128 blocks
// at 256^2 (half-chip idle), so the 128^2 shape stays optimal here.
// ---------------------------------------------------------------------------
template<bool USE_MASK, bool OUT_F32>
__global__ __launch_bounds__(256) void gemm_bt_128(
    const u16* __restrict__ A, int lda,
    const float* __restrict__ amask,  // M fp32
    const u16* __restrict__ Bt,       // N x K row-major bf16 (pre-transposed)
    const float* __restrict__ bias0, const float* __restrict__ bias1,
    void* __restrict__ Cc,            // M x N row-major
    int K, int N)
{
    __shared__ __align__(16) u16 As0[128 * 32];   // 8 KB each, swizzled
    __shared__ __align__(16) u16 As1[128 * 32];
    __shared__ __align__(16) u16 As2[128 * 32];
    __shared__ __align__(16) u16 Bs0[128 * 32];
    __shared__ __align__(16) u16 Bs1[128 * 32];
    __shared__ __align__(16) u16 Bs2[128 * 32];

    const int tid  = threadIdx.x;
    const int wave = tid >> 6;
    const int lane = tid & 63;
    const int row0 = blockIdx.x * 128;
    const int col0 = blockIdx.y * 128;

    const int wm = (wave >> 1) * 64;   // wave's row offset in tile
    const int wn = (wave & 1) * 64;    // wave's col offset in tile

    f32x4 acc[4][4] = {};              // [ci][ri]

    const int quad = lane >> 4;
    const int l16  = lane & 15;

    const int cA = wave * 128 + lane;      // issue 0 chunk
    const int cB = cA + 64;                // issue 1 chunk
    const int rA = cA >> 2, sA = (cA & 3) ^ ((rA >> 1) & 3);
    const int rB = cB >> 2, sB = (cB & 3) ^ ((rB >> 1) & 3);
    const u16* Ag0 = A  + (size_t)(row0 + rA) * lda + sA * 8;
    const u16* Ag1 = A  + (size_t)(row0 + rB) * lda + sB * 8;
    const u16* Bg0 = Bt + (size_t)(col0 + rA) * K   + sA * 8;
    const u16* Bg1 = Bt + (size_t)(col0 + rB) * K   + sB * 8;
    const int ldsOff0 = wave * 1024;       // u16 units: chunk w*128
    const int ldsOff1 = wave * 1024 + 512; // chunk w*128 + 64

#define FR(BUF, R) (*(const bf16x8*)&BUF[swz((R) + l16, quad)])

#define STAGE(SA, SB, KST)                         \
    do {                                           \
        gll16(Ag0 + (KST), &SA[ldsOff0]);          \
        gll16(Ag1 + (KST), &SA[ldsOff1]);          \
        gll16(Bg0 + (KST), &SB[ldsOff0]);          \
        gll16(Bg1 + (KST), &SB[ldsOff1]);          \
    } while (0)

// MODE: 1 = staged this tile, wait vmcnt(4); 0 = drain vmcnt(0); -1 = bare
#define TILE(RA, RB, SA, SB, KST, MODE)                                      \
    do {                                                                     \
        if ((MODE) == 1) STAGE(SA, SB, KST);                                 \
        bf16x8 a[4], b[4];                                                   \
        _Pragma("unroll")                                                    \
        for (int i = 0; i < 4; i++) {                                        \
            a[i] = FR(RA, wm + i * 16);                                      \
            b[i] = FR(RB, wn + i * 16);                                      \
        }                                                                    \
        __builtin_amdgcn_s_setprio(1);                                       \
        _Pragma("unroll")                                                    \
        for (int ci = 0; ci < 4; ci++)                                       \
            _Pragma("unroll")                                                \
            for (int ri = 0; ri < 4; ri++)                                   \
                acc[ci][ri] = __builtin_amdgcn_mfma_f32_16x16x32_bf16(       \
                    b[ci], a[ri], acc[ci][ri], 0, 0, 0);                     \
        __builtin_amdgcn_s_setprio(0);                                       \
        if ((MODE) == 1)      asm volatile("s_waitcnt vmcnt(4)" ::: "memory"); \
        else if ((MODE) == 0) asm volatile("s_waitcnt vmcnt(0)" ::: "memory"); \
        if ((MODE) >= 0) __builtin_amdgcn_s_barrier();                       \
    } while (0)

    // prologue: stage tiles 0 and 1; wait tile 0 landed (vmcnt 4 of 8)
    STAGE(As0, Bs0, 0);
    STAGE(As1, Bs1, 32);
    asm volatile("s_waitcnt vmcnt(4)" ::: "memory");
    __builtin_amdgcn_s_barrier();

    // 16 K-tiles (K = 512): read buf t%3, stage tile t+2 -> buf (t+2)%3
    TILE(As0, Bs0, As2, Bs2,  64, 1);   // t=0
    TILE(As1, Bs1, As0, Bs0,  96, 1);   // t=1
    TILE(As2, Bs2, As1, Bs1, 128, 1);   // t=2
    TILE(As0, Bs0, As2, Bs2, 160, 1);   // t=3
    TILE(As1, Bs1, As0, Bs0, 192, 1);   // t=4
    TILE(As2, Bs2, As1, Bs1, 224, 1);   // t=5
    TILE(As0, Bs0, As2, Bs2, 256, 1);   // t=6
    TILE(As1, Bs1, As0, Bs0, 288, 1);   // t=7
    TILE(As2, Bs2, As1, Bs1, 320, 1);   // t=8
    TILE(As0, Bs0, As2, Bs2, 352, 1);   // t=9
    TILE(As1, Bs1, As0, Bs0, 384, 1);   // t=10
    TILE(As2, Bs2, As1, Bs1, 416, 1);   // t=11
    TILE(As0, Bs0, As2, Bs2, 448, 1);   // t=12
    TILE(As1, Bs1, As0, Bs0, 480, 1);   // t=13 (stages tile 15 -> buf0)
    TILE(As2, Bs2, As0, Bs0,   0, 0);   // t=14 (drain: tile 15 landed)
    TILE(As0, Bs0, As1, Bs1,   0, -1);  // t=15
#undef TILE
#undef STAGE
#undef FR

    // ---- epilogue: register-direct vectorized stores (R9, conflicts=0) ----
    #pragma unroll
    for (int ri = 0; ri < 4; ri++) {
        const int row = row0 + wm + ri * 16 + l16;
        float mval = 1.f;
        if (USE_MASK) mval = amask[row];
        #pragma unroll
        for (int ci = 0; ci < 4; ci++) {
            const int colb = col0 + wn + ci * 16 + quad * 4;
            float4 bv = (colb < 512) ? *(const float4*)(bias0 + colb)
                                     : *(const float4*)(bias1 + colb - 512);
            f32x4 v = acc[ci][ri];
            float v0 = v[0] + bv.x, v1 = v[1] + bv.y,
                  v2 = v[2] + bv.z, v3 = v[3] + bv.w;
            if (USE_MASK) { v0 *= mval; v1 *= mval; v2 *= mval; v3 *= mval; }
            if (OUT_F32) {
                float4 o = make_float4(v0, v1, v2, v3);
                *(float4*)((float*)Cc + (size_t)row * N + colb) = o;
            } else {
                union { uint2 u; u16 s[4]; } o;
                o.s[0] = f2bf(v0); o.s[1] = f2bf(v1);
                o.s[2] = f2bf(v2); o.s[3] = f2bf(v3);
                *(uint2*)((u16*)Cc + (size_t)row * N + colb) = o.u;
            }
        }
    }
}

// ---------------------------------------------------------------------------
// Windowed attention: thread-per-(t,h), k/v staged in LDS [jchunk][row].
// Rows outside [0,T) get the bias row. Output in place over the q slot.
// ---------------------------------------------------------------------------
__global__ __launch_bounds__(256) void attn_win2(u16* __restrict__ qkv,
                                                 const float* __restrict__ bkv)
{
    __shared__ uint4 klds[8 * 270];   // [j][row], row = t0-7+row
    __shared__ uint4 vlds[8 * 270];

    const int tid = threadIdx.x;
    const int bid = blockIdx.x;
    const int h  = bid & 7;
    const int b  = (bid >> 3) & 3;
    const int tb = bid >> 5;          // [0,16)
    const int t0 = tb * 256;

    #pragma unroll
    for (int i = 0; i < 9; i++) {
        int idx = i * 256 + tid;
        if (idx < 2160) {
            int row = idx % 270;
            int j   = idx / 270;
            int tt  = t0 - 7 + row;
            uint4 kc, vc;
            if ((unsigned)tt < (unsigned)T_) {
                const u16* g = qkv + ((size_t)b * T_ + tt) * NQKV + 512 + h * 64 + j * 8;
                kc = *(const uint4*)g;
                vc = *(const uint4*)(g + 512);
            } else {
                union { uint4 u; u16 s[8]; } pk, pv;
                #pragma unroll
                for (int e = 0; e < 8; e++) {
                    pk.s[e] = f2bf(bkv[h * 64 + j * 8 + e]);
                    pv.s[e] = f2bf(bkv[512 + h * 64 + j * 8 + e]);
                }
                kc = pk.u; vc = pv.u;
            }
            klds[j * 270 + row] = kc;
            vlds[j * 270 + row] = vc;
        }
    }
    __syncthreads();

    const size_t m = (size_t)b * T_ + t0 + tid;
    u16* qrow = qkv + m * NQKV + h * 64;

    float qf[64];
    #pragma unroll
    for (int j = 0; j < 8; j++) {
        union { uint4 u; u16 s[8]; } t;
        t.u = *(const uint4*)(qrow + j * 8);
        #pragma unroll
        for (int e = 0; e < 8; e++) qf[j * 8 + e] = bf2f(t.s[e]);
    }

    const float scale = 0.042313283f;   // ln(15)/64
    float s[WIN_];
    #pragma unroll
    for (int w = 0; w < WIN_; w++) {
        float acc = 0.f;
        #pragma unroll
        for (int j = 0; j < 8; j++) {
            union { uint4 u; u16 e[8]; } kc;
            kc.u = klds[j * 270 + tid + w];
            #pragma unroll
            for (int e2 = 0; e2 < 8; e2++)
                acc += qf[j * 8 + e2] * bf2f(kc.e[e2]);
        }
        s[w] = acc * scale;
    }

    float mx = s[0];
    #pragma unroll
    for (int w = 1; w < WIN_; w++) mx = fmaxf(mx, s[w]);
    float sum = 0.f;
    #pragma unroll
    for (int w = 0; w < WIN_; w++) { s[w] = __expf(s[w] - mx); sum += s[w]; }
    const float inv = 1.0f / sum;
    #pragma unroll
    for (int w = 0; w < WIN_; w++) s[w] *= inv;

    #pragma unroll
    for (int j = 0; j < 8; j++) {
        float o[8] = {};
        #pragma unroll
        for (int w = 0; w < WIN_; w++) {
            union { uint4 u; u16 e[8]; } vc;
            vc.u = vlds[j * 270 + tid + w];
            #pragma unroll
            for (int e2 = 0; e2 < 8; e2++) o[e2] += s[w] * bf2f(vc.e[e2]);
        }
        union { uint4 u; u16 e[8]; } oc;
        #pragma unroll
        for (int e2 = 0; e2 < 8; e2++) oc.e[e2] = f2bf(o[e2]);
        *(uint4*)(qrow + j * 8) = oc.u;
    }
}

// ---------------------------------------------------------------------------
// Workspace: 66 MiB total.
//   [0, 1.5Mi)    Wt_qkv (1536x512 bf16)
//   [1.5Mi, 2Mi)  Wpt    (512x512 bf16)
//   [2Mi, 18Mi)   xm     (16384x512 bf16)
//   [18Mi, 66Mi)  qkv    (16384x1536 bf16); q section reused for attn output
// ---------------------------------------------------------------------------
extern "C" void kernel_launch(void* const* d_in, const int* in_sizes, int n_in,
                              void* d_out, int out_size, void* d_ws, size_t ws_size,
                              hipStream_t stream)
{
    const float* x    = (const float*)d_in[0];
    const float* mask = (const float*)d_in[1];
    const float* Wq   = (const float*)d_in[2];
    const float* bq   = (const float*)d_in[3];
    const float* Wkv  = (const float*)d_in[4];
    const float* bkv  = (const float*)d_in[5];
    const float* Wp   = (const float*)d_in[6];
    const float* bp   = (const float*)d_in[7];
    float* out = (float*)d_out;

    char* ws = (char*)d_ws;
    u16* Wt_qkv = (u16*)(ws);
    u16* Wpt    = (u16*)(ws + (size_t)(1536 * 1024));
    u16* xm     = (u16*)(ws + (size_t)(2048 * 1024));
    u16* qkv    = (u16*)(ws + (size_t)(18 * 1024 * 1024));

    pack_weights_t<<<256, 256, 0, stream>>>(Wq, Wkv, Wp, Wt_qkv, Wpt);

    apply_mask<<<(M_ * C_) / (8 * 256), 256, 0, stream>>>(x, mask, xm);

    // GEMM1: 256^2 8-wave phase-interleaved kernel; grid 64x6 (=384 blocks,
    // gridDim.x % 8 == 0 keeps natural per-XCD A-panel L2 affinity [R16])
    dim3 g1(M_ / 256, NQKV / 256);
    gemm1_256<<<g1, 512, 0, stream>>>(xm, Wt_qkv, bq, bkv, qkv);

    attn_win2<<<(T_ / 256) * B_ * H_, 256, 0, stream>>>(qkv, bkv);

    // GEMM2: proven 128^2 kernel (512 blocks; 256^2 would leave half idle)
    dim3 g2(M_ / 128, C_ / 128);
    gemm_bt_128<true, true><<<g2, 256, 0, stream>>>(
        qkv, NQKV, mask, Wpt, bp, nullptr, out, KDIM, C_);
}

// Round 7
// 187.592 us; speedup vs baseline: 1.0397x; 1.0397x over previous
//
#include <hip/hip_runtime.h>
#include <hip/hip_bf16.h>

typedef unsigned short u16;

#define B_    4
#define T_    4096
#define C_    512
#define H_    8
#define D_    64
#define WIN_  15
#define PAD_  7
#define M_    (B_*T_)      // 16384 rows
#define NQKV  1536
#define KDIM  512

typedef __bf16 bf16x8 __attribute__((ext_vector_type(8)));
typedef float  f32x4  __attribute__((ext_vector_type(4)));

__device__ __forceinline__ u16 f2bf(float f) {
    union { float f; unsigned int i; } c; c.f = f;
    unsigned int lsb = (c.i >> 16) & 1u;
    c.i += 0x7fffu + lsb;                 // round-to-nearest-even
    return (u16)(c.i >> 16);
}
__device__ __forceinline__ float bf2f(u16 u) {
    union { unsigned int i; float f; } c; c.i = ((unsigned int)u) << 16; return c.f;
}

// BK=32 swizzle for the 128^2 kernel (verified R9).
__device__ __forceinline__ int swz(int row, int sub) {
    return (row * 4 + (sub ^ ((row >> 1) & 3))) * 8;
}

// global->LDS direct DMA, 16B per lane, dest = wave-uniform base + lane*16
__device__ __forceinline__ void gll16(const void* g, void* l) {
    __builtin_amdgcn_global_load_lds(
        (const __attribute__((address_space(1))) void*)g,
        (__attribute__((address_space(3))) void*)l, 16, 0, 0);
}

// ---------------------------------------------------------------------------
// R15: coalesced weight pack via LDS 64x64 tile transpose. (verified)
// ---------------------------------------------------------------------------
__global__ __launch_bounds__(256) void pack_weights_t(
    const float* __restrict__ Wq, const float* __restrict__ Wkv,
    const float* __restrict__ Wp,
    u16* __restrict__ Wt_qkv, u16* __restrict__ Wpt)
{
    __shared__ float tile[64][65];
    const int bid = blockIdx.x;
    const float* src; int srcld; u16* dst; int n0, k0;
    if (bid < 192) {            // Wt_qkv: n0 in [0,1536), k0 in [0,512)
        n0 = (bid % 24) * 64; k0 = (bid / 24) * 64;
        dst = Wt_qkv;
        if (n0 < 512) { src = Wq + n0;          srcld = 512;  }
        else          { src = Wkv + (n0 - 512); srcld = 1024; }
    } else {                    // Wpt
        const int b2 = bid - 192;
        n0 = (b2 % 8) * 64; k0 = (b2 / 8) * 64;
        dst = Wpt; src = Wp + n0; srcld = 512;
    }
    const int tr = threadIdx.x >> 6;   // 0..3
    const int tc = threadIdx.x & 63;
    #pragma unroll
    for (int p = 0; p < 16; p++) {
        const int kk = p * 4 + tr;
        tile[kk][tc] = src[(size_t)(k0 + kk) * srcld + tc];
    }
    __syncthreads();
    #pragma unroll
    for (int p = 0; p < 16; p++) {
        const int nn = p * 4 + tr;
        dst[(size_t)(n0 + nn) * 512 + k0 + tc] = f2bf(tile[tc][nn]);
    }
}

// ---------------------------------------------------------------------------
// xm = bf16( x_fp32 * mask[row] ) — one-time pass so GEMM1 never re-converts.
// ---------------------------------------------------------------------------
__global__ void apply_mask(const float* __restrict__ x, const float* __restrict__ mask,
                           u16* __restrict__ xm)
{
    int idx = blockIdx.x * blockDim.x + threadIdx.x;   // one per 8 elems
    int e0 = idx * 8;
    float mval = mask[e0 >> 9];
    float4 a = *(const float4*)(x + e0);
    float4 b = *(const float4*)(x + e0 + 4);
    union { uint4 u; u16 s[8]; } o;
    o.s[0] = f2bf(a.x * mval); o.s[1] = f2bf(a.y * mval);
    o.s[2] = f2bf(a.z * mval); o.s[3] = f2bf(a.w * mval);
    o.s[4] = f2bf(b.x * mval); o.s[5] = f2bf(b.y * mval);
    o.s[6] = f2bf(b.z * mval); o.s[7] = f2bf(b.w * mval);
    *(uint4*)(xm + e0) = o.u;
}

// ---------------------------------------------------------------------------
// GEMM1 (R16, proven 46.1 us): 128x128, 4 waves, 2D grid, triple-buffer
// counted-vmcnt ledger, one s_barrier per K-step. Natural round-robin with
// gridDim.x=128 (%8==0) pins row-block r to XCD r%8 -> A-panel L2 affinity.
// ---------------------------------------------------------------------------
template<bool USE_MASK, bool OUT_F32>
__global__ __launch_bounds__(256) void gemm_bt_128(
    const u16* __restrict__ A, int lda,
    const float* __restrict__ amask,
    const u16* __restrict__ Bt,
    const float* __restrict__ bias0, const float* __restrict__ bias1,
    void* __restrict__ Cc,
    int K, int N)
{
    __shared__ __align__(16) u16 As0[128 * 32];
    __shared__ __align__(16) u16 As1[128 * 32];
    __shared__ __align__(16) u16 As2[128 * 32];
    __shared__ __align__(16) u16 Bs0[128 * 32];
    __shared__ __align__(16) u16 Bs1[128 * 32];
    __shared__ __align__(16) u16 Bs2[128 * 32];

    const int tid  = threadIdx.x;
    const int wave = tid >> 6;
    const int lane = tid & 63;
    const int row0 = blockIdx.x * 128;
    const int col0 = blockIdx.y * 128;

    const int wm = (wave >> 1) * 64;
    const int wn = (wave & 1) * 64;

    f32x4 acc[4][4] = {};

    const int quad = lane >> 4;
    const int l16  = lane & 15;

    const int cA = wave * 128 + lane;
    const int cB = cA + 64;
    const int rA = cA >> 2, sA = (cA & 3) ^ ((rA >> 1) & 3);
    const int rB = cB >> 2, sB = (cB & 3) ^ ((rB >> 1) & 3);
    const u16* Ag0 = A  + (size_t)(row0 + rA) * lda + sA * 8;
    const u16* Ag1 = A  + (size_t)(row0 + rB) * lda + sB * 8;
    const u16* Bg0 = Bt + (size_t)(col0 + rA) * K   + sA * 8;
    const u16* Bg1 = Bt + (size_t)(col0 + rB) * K   + sB * 8;
    const int ldsOff0 = wave * 1024;
    const int ldsOff1 = wave * 1024 + 512;

#define FR(BUF, R) (*(const bf16x8*)&BUF[swz((R) + l16, quad)])

#define STAGE(SA, SB, KST)                         \
    do {                                           \
        gll16(Ag0 + (KST), &SA[ldsOff0]);          \
        gll16(Ag1 + (KST), &SA[ldsOff1]);          \
        gll16(Bg0 + (KST), &SB[ldsOff0]);          \
        gll16(Bg1 + (KST), &SB[ldsOff1]);          \
    } while (0)

#define TILE(RA, RB, SA, SB, KST, MODE)                                      \
    do {                                                                     \
        if ((MODE) == 1) STAGE(SA, SB, KST);                                 \
        bf16x8 a[4], b[4];                                                   \
        _Pragma("unroll")                                                    \
        for (int i = 0; i < 4; i++) {                                        \
            a[i] = FR(RA, wm + i * 16);                                      \
            b[i] = FR(RB, wn + i * 16);                                      \
        }                                                                    \
        __builtin_amdgcn_s_setprio(1);                                       \
        _Pragma("unroll")                                                    \
        for (int ci = 0; ci < 4; ci++)                                       \
            _Pragma("unroll")                                                \
            for (int ri = 0; ri < 4; ri++)                                   \
                acc[ci][ri] = __builtin_amdgcn_mfma_f32_16x16x32_bf16(       \
                    b[ci], a[ri], acc[ci][ri], 0, 0, 0);                     \
        __builtin_amdgcn_s_setprio(0);                                       \
        if ((MODE) == 1)      asm volatile("s_waitcnt vmcnt(4)" ::: "memory"); \
        else if ((MODE) == 0) asm volatile("s_waitcnt vmcnt(0)" ::: "memory"); \
        if ((MODE) >= 0) __builtin_amdgcn_s_barrier();                       \
    } while (0)

    STAGE(As0, Bs0, 0);
    STAGE(As1, Bs1, 32);
    asm volatile("s_waitcnt vmcnt(4)" ::: "memory");
    __builtin_amdgcn_s_barrier();

    TILE(As0, Bs0, As2, Bs2,  64, 1);
    TILE(As1, Bs1, As0, Bs0,  96, 1);
    TILE(As2, Bs2, As1, Bs1, 128, 1);
    TILE(As0, Bs0, As2, Bs2, 160, 1);
    TILE(As1, Bs1, As0, Bs0, 192, 1);
    TILE(As2, Bs2, As1, Bs1, 224, 1);
    TILE(As0, Bs0, As2, Bs2, 256, 1);
    TILE(As1, Bs1, As0, Bs0, 288, 1);
    TILE(As2, Bs2, As1, Bs1, 320, 1);
    TILE(As0, Bs0, As2, Bs2, 352, 1);
    TILE(As1, Bs1, As0, Bs0, 384, 1);
    TILE(As2, Bs2, As1, Bs1, 416, 1);
    TILE(As0, Bs0, As2, Bs2, 448, 1);
    TILE(As1, Bs1, As0, Bs0, 480, 1);
    TILE(As2, Bs2, As0, Bs0,   0, 0);
    TILE(As0, Bs0, As1, Bs1,   0, -1);
#undef TILE
#undef STAGE
#undef FR

    #pragma unroll
    for (int ri = 0; ri < 4; ri++) {
        const int row = row0 + wm + ri * 16 + l16;
        float mval = 1.f;
        if (USE_MASK) mval = amask[row];
        #pragma unroll
        for (int ci = 0; ci < 4; ci++) {
            const int colb = col0 + wn + ci * 16 + quad * 4;
            float4 bv = (colb < 512) ? *(const float4*)(bias0 + colb)
                                     : *(const float4*)(bias1 + colb - 512);
            f32x4 v = acc[ci][ri];
            float v0 = v[0] + bv.x, v1 = v[1] + bv.y,
                  v2 = v[2] + bv.z, v3 = v[3] + bv.w;
            if (USE_MASK) { v0 *= mval; v1 *= mval; v2 *= mval; v3 *= mval; }
            if (OUT_F32) {
                float4 o = make_float4(v0, v1, v2, v3);
                *(float4*)((float*)Cc + (size_t)row * N + colb) = o;
            } else {
                union { uint2 u; u16 s[4]; } o;
                o.s[0] = f2bf(v0); o.s[1] = f2bf(v1);
                o.s[2] = f2bf(v2); o.s[3] = f2bf(v3);
                *(uint2*)((u16*)Cc + (size_t)row * N + colb) = o.u;
            }
        }
    }
}

// ---------------------------------------------------------------------------
// R18 GEMM2: 256x128 tile, 8 waves (4M x 2N, each 64x64 = the verified
// fragment geometry), BK=64, RING-3 LDS (144 KB), fine 2-phase K-tiles.
// Why this shape: grid = (16384/256) x (512/128) = 64x4 = 256 blocks =
// EXACTLY 1 block/CU, one full round (R6 post-mortem: the 256^2 schedule won
// +22%/CU but lost it to 1.5-round fill; GEMM2's N=512 permits exact fill).
// Ledger (R5's proven pattern, stm units: 6 gll per K-tile):
//   tile t reads buf t%3; stages tile t+2 -> buf (t+2)%3 (free: consumed at
//   t-1). End-of-tile s_waitcnt vmcnt(6): 12 outstanding max -> oldest 6
//   (= tile t+1's) landed. Never 0 until the tail (t=6).
//   Prologue: stage t0,t1 (12 stm), vmcnt(6) (t0 landed), barrier.
// Phases per K-tile: ph-a = kh0 (16 MFMA), ph-b = kh1 (16 MFMA); each phase:
//   {8 ds_read_b128 | 3 gll stage} -> barrier -> lgkmcnt(0) -> setprio(1)
//   -> 16 MFMA -> setprio(0) -> [vmcnt] -> barrier.   (T3+T4+T5)
// Swizzle: per-row involution slot = sub ^ (row&7) (R6-verified): staging
// pre-swizzles the global source; reads at slot (kh*4+quad)^(l16&7) are
// <=2-way bank spread (free per m136).
// MFMA as mfma(b, a, acc): lane&15 -> C row, quad*4+reg -> C col [R9].
// ---------------------------------------------------------------------------
__global__ __launch_bounds__(512, 2) void gemm2_256x128(
    const u16* __restrict__ A,        // qkv, 16384 x 1536 (lda 1536)
    const u16* __restrict__ Bt,       // Wpt, 512 x 512
    const float* __restrict__ bp,
    const float* __restrict__ amask,
    float* __restrict__ out)          // 16384 x 512 fp32
{
    __shared__ __align__(16) u16 A0[256 * 64];   // 32 KB each
    __shared__ __align__(16) u16 A1[256 * 64];
    __shared__ __align__(16) u16 A2[256 * 64];
    __shared__ __align__(16) u16 B0[128 * 64];   // 16 KB each
    __shared__ __align__(16) u16 B1[128 * 64];
    __shared__ __align__(16) u16 B2[128 * 64];

    const int tid  = threadIdx.x;
    const int wave = tid >> 6;
    const int lane = tid & 63;
    const int quad = lane >> 4;
    const int l16  = lane & 15;
    const int row0 = blockIdx.x * 256;
    const int col0 = blockIdx.y * 128;
    const int wm = (wave >> 1) * 64;   // 4 M-groups
    const int wn = (wave & 1) * 64;    // 2 N-groups

    f32x4 acc[4][4] = {};              // [rg][cg]

    // staging: stm s covers rows s*64..s*64+63 of the tile; lane chunk =
    // s*512 + tid -> row = s*64 + (tid>>3), slot = tid&7 holds src sub
    // slot ^ (row&7) (row&7 == (tid>>3)&7 for every s).
    const int rowi = tid >> 3;                       // 0..63
    const int subx = (tid & 7) ^ (rowi & 7);
    const u16* Ag = A  + (size_t)(row0 + rowi) * NQKV + subx * 8;
    const u16* Bg = Bt + (size_t)(col0 + rowi) * 512  + subx * 8;
    const int so = wave * 512;                       // u16, wave-uniform

    // fragment read offsets (u16)
    const int aoff = (wm + l16) * 64;
    const int boff = (wn + l16) * 64;
    const int sk0 = ((0 + quad) ^ (l16 & 7)) * 8;    // kh=0 (k 0..31)
    const int sk1 = ((4 + quad) ^ (l16 & 7)) * 8;    // kh=1 (k 32..63)

#define SA_(BUF, s, KK) gll16(Ag + (size_t)(s) * 64 * NQKV + (KK), &BUF[(s) * 4096 + so])
#define SB_(BUF, s, KK) gll16(Bg + (size_t)(s) * 64 * 512  + (KK), &BUF[(s) * 4096 + so])

#define BAR2 __builtin_amdgcn_s_barrier()
#define LGK2 do { asm volatile("s_waitcnt lgkmcnt(0)" ::: "memory");          \
                  __builtin_amdgcn_sched_barrier(0); } while (0)

#define PH2(AB, BB, SK, STGS) do {                                            \
    bf16x8 aF[4], bF[4];                                                      \
    _Pragma("unroll")                                                         \
    for (int rg = 0; rg < 4; rg++)                                            \
        aF[rg] = *(const bf16x8*)&AB[aoff + rg * 1024 + (SK)];                \
    _Pragma("unroll")                                                         \
    for (int cg = 0; cg < 4; cg++)                                            \
        bF[cg] = *(const bf16x8*)&BB[boff + cg * 1024 + (SK)];                \
    STGS;                                                                     \
    BAR2; LGK2;                                                               \
    __builtin_amdgcn_s_setprio(1);                                            \
    _Pragma("unroll")                                                         \
    for (int rg = 0; rg < 4; rg++)                                            \
        _Pragma("unroll")                                                     \
        for (int cg = 0; cg < 4; cg++)                                        \
            acc[rg][cg] = __builtin_amdgcn_mfma_f32_16x16x32_bf16(            \
                bF[cg], aF[rg], acc[rg][cg], 0, 0, 0);                        \
    __builtin_amdgcn_s_setprio(0);                                            \
} while (0)

// one K-tile: read (AB,BB); stage tile t+2 into (SA,SB) at k-offset KK.
// WK: 6 = counted vmcnt(6); 0 = drain; -1 = none.
#define TILE2(AB, BB, SA, SB, KK, DO, WK) do {                                \
    PH2(AB, BB, sk0,                                                          \
        if (DO) { SA_(SA, 0, KK); SA_(SA, 1, KK); SA_(SA, 2, KK); });         \
    BAR2;                                                                     \
    PH2(AB, BB, sk1,                                                          \
        if (DO) { SA_(SA, 3, KK); SB_(SB, 0, KK); SB_(SB, 1, KK); });         \
    if ((WK) == 6)      asm volatile("s_waitcnt vmcnt(6)" ::: "memory");      \
    else if ((WK) == 0) asm volatile("s_waitcnt vmcnt(0)" ::: "memory");      \
    BAR2;                                                                     \
} while (0)

    // prologue: stage tiles 0,1 (12 stm); vmcnt(6) -> tile 0 landed
    SA_(A0, 0, 0);  SA_(A0, 1, 0);  SA_(A0, 2, 0);  SA_(A0, 3, 0);
    SB_(B0, 0, 0);  SB_(B0, 1, 0);
    SA_(A1, 0, 64); SA_(A1, 1, 64); SA_(A1, 2, 64); SA_(A1, 3, 64);
    SB_(B1, 0, 64); SB_(B1, 1, 64);
    asm volatile("s_waitcnt vmcnt(6)" ::: "memory");
    __builtin_amdgcn_s_barrier();

    // 8 K-tiles (K=512, BK=64), ring-3
    TILE2(A0, B0, A2, B2, 128, 1, 6);   // t0 stages t2
    TILE2(A1, B1, A0, B0, 192, 1, 6);   // t1 stages t3
    TILE2(A2, B2, A1, B1, 256, 1, 6);   // t2 stages t4
    TILE2(A0, B0, A2, B2, 320, 1, 6);   // t3 stages t5
    TILE2(A1, B1, A0, B0, 384, 1, 6);   // t4 stages t6
    TILE2(A2, B2, A1, B1, 448, 1, 6);   // t5 stages t7
    TILE2(A0, B0, A1, B1,   0, 0, 0);   // t6 (drain: t7 landed)
    TILE2(A1, B1, A2, B2,   0, 0, -1);  // t7
#undef TILE2
#undef PH2
#undef SA_
#undef SB_
#undef BAR2
#undef LGK2

    // epilogue: bias + row mask, fp32 float4 stores (register-direct)
    #pragma unroll
    for (int rg = 0; rg < 4; rg++) {
        const int row = row0 + wm + rg * 16 + l16;
        const float mval = amask[row];
        #pragma unroll
        for (int cg = 0; cg < 4; cg++) {
            const int colb = col0 + wn + cg * 16 + quad * 4;
            float4 bv = *(const float4*)(bp + colb);
            f32x4 v = acc[rg][cg];
            float4 o = make_float4((v[0] + bv.x) * mval, (v[1] + bv.y) * mval,
                                   (v[2] + bv.z) * mval, (v[3] + bv.w) * mval);
            *(float4*)(out + (size_t)row * 512 + colb) = o;
        }
    }
}

// ---------------------------------------------------------------------------
// Windowed attention: thread-per-(t,h), k/v staged in LDS [jchunk][row].
// ---------------------------------------------------------------------------
__global__ __launch_bounds__(256) void attn_win2(u16* __restrict__ qkv,
                                                 const float* __restrict__ bkv)
{
    __shared__ uint4 klds[8 * 270];
    __shared__ uint4 vlds[8 * 270];

    const int tid = threadIdx.x;
    const int bid = blockIdx.x;
    const int h  = bid & 7;
    const int b  = (bid >> 3) & 3;
    const int tb = bid >> 5;
    const int t0 = tb * 256;

    #pragma unroll
    for (int i = 0; i < 9; i++) {
        int idx = i * 256 + tid;
        if (idx < 2160) {
            int row = idx % 270;
            int j   = idx / 270;
            int tt  = t0 - 7 + row;
            uint4 kc, vc;
            if ((unsigned)tt < (unsigned)T_) {
                const u16* g = qkv + ((size_t)b * T_ + tt) * NQKV + 512 + h * 64 + j * 8;
                kc = *(const uint4*)g;
                vc = *(const uint4*)(g + 512);
            } else {
                union { uint4 u; u16 s[8]; } pk, pv;
                #pragma unroll
                for (int e = 0; e < 8; e++) {
                    pk.s[e] = f2bf(bkv[h * 64 + j * 8 + e]);
                    pv.s[e] = f2bf(bkv[512 + h * 64 + j * 8 + e]);
                }
                kc = pk.u; vc = pv.u;
            }
            klds[j * 270 + row] = kc;
            vlds[j * 270 + row] = vc;
        }
    }
    __syncthreads();

    const size_t m = (size_t)b * T_ + t0 + tid;
    u16* qrow = qkv + m * NQKV + h * 64;

    float qf[64];
    #pragma unroll
    for (int j = 0; j < 8; j++) {
        union { uint4 u; u16 s[8]; } t;
        t.u = *(const uint4*)(qrow + j * 8);
        #pragma unroll
        for (int e = 0; e < 8; e++) qf[j * 8 + e] = bf2f(t.s[e]);
    }

    const float scale = 0.042313283f;   // ln(15)/64
    float s[WIN_];
    #pragma unroll
    for (int w = 0; w < WIN_; w++) {
        float acc = 0.f;
        #pragma unroll
        for (int j = 0; j < 8; j++) {
            union { uint4 u; u16 e[8]; } kc;
            kc.u = klds[j * 270 + tid + w];
            #pragma unroll
            for (int e2 = 0; e2 < 8; e2++)
                acc += qf[j * 8 + e2] * bf2f(kc.e[e2]);
        }
        s[w] = acc * scale;
    }

    float mx = s[0];
    #pragma unroll
    for (int w = 1; w < WIN_; w++) mx = fmaxf(mx, s[w]);
    float sum = 0.f;
    #pragma unroll
    for (int w = 0; w < WIN_; w++) { s[w] = __expf(s[w] - mx); sum += s[w]; }
    const float inv = 1.0f / sum;
    #pragma unroll
    for (int w = 0; w < WIN_; w++) s[w] *= inv;

    #pragma unroll
    for (int j = 0; j < 8; j++) {
        float o[8] = {};
        #pragma unroll
        for (int w = 0; w < WIN_; w++) {
            union { uint4 u; u16 e[8]; } vc;
            vc.u = vlds[j * 270 + tid + w];
            #pragma unroll
            for (int e2 = 0; e2 < 8; e2++) o[e2] += s[w] * bf2f(vc.e[e2]);
        }
        union { uint4 u; u16 e[8]; } oc;
        #pragma unroll
        for (int e2 = 0; e2 < 8; e2++) oc.e[e2] = f2bf(o[e2]);
        *(uint4*)(qrow + j * 8) = oc.u;
    }
}

// ---------------------------------------------------------------------------
// Workspace: 66 MiB total.
//   [0, 1.5Mi)    Wt_qkv (1536x512 bf16)
//   [1.5Mi, 2Mi)  Wpt    (512x512 bf16)
//   [2Mi, 18Mi)   xm     (16384x512 bf16)
//   [18Mi, 66Mi)  qkv    (16384x1536 bf16); q section reused for attn output
// ---------------------------------------------------------------------------
extern "C" void kernel_launch(void* const* d_in, const int* in_sizes, int n_in,
                              void* d_out, int out_size, void* d_ws, size_t ws_size,
                              hipStream_t stream)
{
    const float* x    = (const float*)d_in[0];
    const float* mask = (const float*)d_in[1];
    const float* Wq   = (const float*)d_in[2];
    const float* bq   = (const float*)d_in[3];
    const float* Wkv  = (const float*)d_in[4];
    const float* bkv  = (const float*)d_in[5];
    const float* Wp   = (const float*)d_in[6];
    const float* bp   = (const float*)d_in[7];
    float* out = (float*)d_out;

    char* ws = (char*)d_ws;
    u16* Wt_qkv = (u16*)(ws);
    u16* Wpt    = (u16*)(ws + (size_t)(1536 * 1024));
    u16* xm     = (u16*)(ws + (size_t)(2048 * 1024));
    u16* qkv    = (u16*)(ws + (size_t)(18 * 1024 * 1024));

    pack_weights_t<<<256, 256, 0, stream>>>(Wq, Wkv, Wp, Wt_qkv, Wpt);

    apply_mask<<<(M_ * C_) / (8 * 256), 256, 0, stream>>>(x, mask, xm);

    // GEMM1: proven 128^2 ledger kernel, 2D grid (natural XCD A-affinity)
    dim3 g1(M_ / 128, NQKV / 128);
    gemm_bt_128<false, false><<<g1, 256, 0, stream>>>(
        xm, KDIM, mask, Wt_qkv, bq, bkv, qkv, KDIM, NQKV);

    attn_win2<<<(T_ / 256) * B_ * H_, 256, 0, stream>>>(qkv, bkv);

    // GEMM2: 256x128 phased kernel, grid 64x4 = 256 blocks = exact 1/CU fill
    dim3 g2(M_ / 256, C_ / 128);
    gemm2_256x128<<<g2, 512, 0, stream>>>(qkv, Wpt, bp, mask, out);
}

// Round 8
// 173.699 us; speedup vs baseline: 1.1229x; 1.0800x over previous
//
#include <hip/hip_runtime.h>
#include <hip/hip_bf16.h>

typedef unsigned short u16;

#define B_    4
#define T_    4096
#define C_    512
#define H_    8
#define D_    64
#define WIN_  15
#define PAD_  7
#define M_    (B_*T_)      // 16384 rows
#define NQKV  1536
#define KDIM  512

typedef __bf16 bf16x8 __attribute__((ext_vector_type(8)));
typedef float  f32x4  __attribute__((ext_vector_type(4)));

__device__ __forceinline__ u16 f2bf(float f) {
    union { float f; unsigned int i; } c; c.f = f;
    unsigned int lsb = (c.i >> 16) & 1u;
    c.i += 0x7fffu + lsb;                 // round-to-nearest-even
    return (u16)(c.i >> 16);
}
__device__ __forceinline__ float bf2f(u16 u) {
    union { unsigned int i; float f; } c; c.i = ((unsigned int)u) << 16; return c.f;
}

// BK=32 swizzle for the 128^2 kernel (verified R9).
__device__ __forceinline__ int swz(int row, int sub) {
    return (row * 4 + (sub ^ ((row >> 1) & 3))) * 8;
}

// global->LDS direct DMA, 16B per lane, dest = wave-uniform base + lane*16
__device__ __forceinline__ void gll16(const void* g, void* l) {
    __builtin_amdgcn_global_load_lds(
        (const __attribute__((address_space(1))) void*)g,
        (__attribute__((address_space(3))) void*)l, 16, 0, 0);
}

// ---------------------------------------------------------------------------
// R15: coalesced weight pack via LDS 64x64 tile transpose. (verified)
// ---------------------------------------------------------------------------
__global__ __launch_bounds__(256) void pack_weights_t(
    const float* __restrict__ Wq, const float* __restrict__ Wkv,
    const float* __restrict__ Wp,
    u16* __restrict__ Wt_qkv, u16* __restrict__ Wpt)
{
    __shared__ float tile[64][65];
    const int bid = blockIdx.x;
    const float* src; int srcld; u16* dst; int n0, k0;
    if (bid < 192) {            // Wt_qkv: n0 in [0,1536), k0 in [0,512)
        n0 = (bid % 24) * 64; k0 = (bid / 24) * 64;
        dst = Wt_qkv;
        if (n0 < 512) { src = Wq + n0;          srcld = 512;  }
        else          { src = Wkv + (n0 - 512); srcld = 1024; }
    } else {                    // Wpt
        const int b2 = bid - 192;
        n0 = (b2 % 8) * 64; k0 = (b2 / 8) * 64;
        dst = Wpt; src = Wp + n0; srcld = 512;
    }
    const int tr = threadIdx.x >> 6;   // 0..3
    const int tc = threadIdx.x & 63;
    #pragma unroll
    for (int p = 0; p < 16; p++) {
        const int kk = p * 4 + tr;
        tile[kk][tc] = src[(size_t)(k0 + kk) * srcld + tc];
    }
    __syncthreads();
    #pragma unroll
    for (int p = 0; p < 16; p++) {
        const int nn = p * 4 + tr;
        dst[(size_t)(n0 + nn) * 512 + k0 + tc] = f2bf(tile[tc][nn]);
    }
}

// ---------------------------------------------------------------------------
// xm = bf16( x_fp32 * mask[row] ) — one-time pass so GEMM1 never re-converts.
// ---------------------------------------------------------------------------
__global__ void apply_mask(const float* __restrict__ x, const float* __restrict__ mask,
                           u16* __restrict__ xm)
{
    int idx = blockIdx.x * blockDim.x + threadIdx.x;   // one per 8 elems
    int e0 = idx * 8;
    float mval = mask[e0 >> 9];
    float4 a = *(const float4*)(x + e0);
    float4 b = *(const float4*)(x + e0 + 4);
    union { uint4 u; u16 s[8]; } o;
    o.s[0] = f2bf(a.x * mval); o.s[1] = f2bf(a.y * mval);
    o.s[2] = f2bf(a.z * mval); o.s[3] = f2bf(a.w * mval);
    o.s[4] = f2bf(b.x * mval); o.s[5] = f2bf(b.y * mval);
    o.s[6] = f2bf(b.z * mval); o.s[7] = f2bf(b.w * mval);
    *(uint4*)(xm + e0) = o.u;
}

// ---------------------------------------------------------------------------
// GEMM1 (R16, proven 45.3 us): 128x128, 4 waves, 2D grid, triple-buffer
// counted-vmcnt ledger, one s_barrier per K-step. Natural round-robin with
// gridDim.x=128 (%8==0) pins row-block r to XCD r%8 -> A-panel L2 affinity.
// ---------------------------------------------------------------------------
template<bool USE_MASK, bool OUT_F32>
__global__ __launch_bounds__(256) void gemm_bt_128(
    const u16* __restrict__ A, int lda,
    const float* __restrict__ amask,
    const u16* __restrict__ Bt,
    const float* __restrict__ bias0, const float* __restrict__ bias1,
    void* __restrict__ Cc,
    int K, int N)
{
    __shared__ __align__(16) u16 As0[128 * 32];
    __shared__ __align__(16) u16 As1[128 * 32];
    __shared__ __align__(16) u16 As2[128 * 32];
    __shared__ __align__(16) u16 Bs0[128 * 32];
    __shared__ __align__(16) u16 Bs1[128 * 32];
    __shared__ __align__(16) u16 Bs2[128 * 32];

    const int tid  = threadIdx.x;
    const int wave = tid >> 6;
    const int lane = tid & 63;
    const int row0 = blockIdx.x * 128;
    const int col0 = blockIdx.y * 128;

    const int wm = (wave >> 1) * 64;
    const int wn = (wave & 1) * 64;

    f32x4 acc[4][4] = {};

    const int quad = lane >> 4;
    const int l16  = lane & 15;

    const int cA = wave * 128 + lane;
    const int cB = cA + 64;
    const int rA = cA >> 2, sA = (cA & 3) ^ ((rA >> 1) & 3);
    const int rB = cB >> 2, sB = (cB & 3) ^ ((rB >> 1) & 3);
    const u16* Ag0 = A  + (size_t)(row0 + rA) * lda + sA * 8;
    const u16* Ag1 = A  + (size_t)(row0 + rB) * lda + sB * 8;
    const u16* Bg0 = Bt + (size_t)(col0 + rA) * K   + sA * 8;
    const u16* Bg1 = Bt + (size_t)(col0 + rB) * K   + sB * 8;
    const int ldsOff0 = wave * 1024;
    const int ldsOff1 = wave * 1024 + 512;

#define FR(BUF, R) (*(const bf16x8*)&BUF[swz((R) + l16, quad)])

#define STAGE(SA, SB, KST)                         \
    do {                                           \
        gll16(Ag0 + (KST), &SA[ldsOff0]);          \
        gll16(Ag1 + (KST), &SA[ldsOff1]);          \
        gll16(Bg0 + (KST), &SB[ldsOff0]);          \
        gll16(Bg1 + (KST), &SB[ldsOff1]);          \
    } while (0)

#define TILE(RA, RB, SA, SB, KST, MODE)                                      \
    do {                                                                     \
        if ((MODE) == 1) STAGE(SA, SB, KST);                                 \
        bf16x8 a[4], b[4];                                                   \
        _Pragma("unroll")                                                    \
        for (int i = 0; i < 4; i++) {                                        \
            a[i] = FR(RA, wm + i * 16);                                      \
            b[i] = FR(RB, wn + i * 16);                                      \
        }                                                                    \
        __builtin_amdgcn_s_setprio(1);                                       \
        _Pragma("unroll")                                                    \
        for (int ci = 0; ci < 4; ci++)                                       \
            _Pragma("unroll")                                                \
            for (int ri = 0; ri < 4; ri++)                                   \
                acc[ci][ri] = __builtin_amdgcn_mfma_f32_16x16x32_bf16(       \
                    b[ci], a[ri], acc[ci][ri], 0, 0, 0);                     \
        __builtin_amdgcn_s_setprio(0);                                       \
        if ((MODE) == 1)      asm volatile("s_waitcnt vmcnt(4)" ::: "memory"); \
        else if ((MODE) == 0) asm volatile("s_waitcnt vmcnt(0)" ::: "memory"); \
        if ((MODE) >= 0) __builtin_amdgcn_s_barrier();                       \
    } while (0)

    STAGE(As0, Bs0, 0);
    STAGE(As1, Bs1, 32);
    asm volatile("s_waitcnt vmcnt(4)" ::: "memory");
    __builtin_amdgcn_s_barrier();

    TILE(As0, Bs0, As2, Bs2,  64, 1);
    TILE(As1, Bs1, As0, Bs0,  96, 1);
    TILE(As2, Bs2, As1, Bs1, 128, 1);
    TILE(As0, Bs0, As2, Bs2, 160, 1);
    TILE(As1, Bs1, As0, Bs0, 192, 1);
    TILE(As2, Bs2, As1, Bs1, 224, 1);
    TILE(As0, Bs0, As2, Bs2, 256, 1);
    TILE(As1, Bs1, As0, Bs0, 288, 1);
    TILE(As2, Bs2, As1, Bs1, 320, 1);
    TILE(As0, Bs0, As2, Bs2, 352, 1);
    TILE(As1, Bs1, As0, Bs0, 384, 1);
    TILE(As2, Bs2, As1, Bs1, 416, 1);
    TILE(As0, Bs0, As2, Bs2, 448, 1);
    TILE(As1, Bs1, As0, Bs0, 480, 1);
    TILE(As2, Bs2, As0, Bs0,   0, 0);
    TILE(As0, Bs0, As1, Bs1,   0, -1);
#undef TILE
#undef STAGE
#undef FR

    #pragma unroll
    for (int ri = 0; ri < 4; ri++) {
        const int row = row0 + wm + ri * 16 + l16;
        float mval = 1.f;
        if (USE_MASK) mval = amask[row];
        #pragma unroll
        for (int ci = 0; ci < 4; ci++) {
            const int colb = col0 + wn + ci * 16 + quad * 4;
            float4 bv = (colb < 512) ? *(const float4*)(bias0 + colb)
                                     : *(const float4*)(bias1 + colb - 512);
            f32x4 v = acc[ci][ri];
            float v0 = v[0] + bv.x, v1 = v[1] + bv.y,
                  v2 = v[2] + bv.z, v3 = v[3] + bv.w;
            if (USE_MASK) { v0 *= mval; v1 *= mval; v2 *= mval; v3 *= mval; }
            if (OUT_F32) {
                float4 o = make_float4(v0, v1, v2, v3);
                *(float4*)((float*)Cc + (size_t)row * N + colb) = o;
            } else {
                union { uint2 u; u16 s[4]; } o;
                o.s[0] = f2bf(v0); o.s[1] = f2bf(v1);
                o.s[2] = f2bf(v2); o.s[3] = f2bf(v3);
                *(uint2*)((u16*)Cc + (size_t)row * N + colb) = o.u;
            }
        }
    }
}

// ---------------------------------------------------------------------------
// R18 GEMM2 (proven: dropped out of top-5): 256x128 tile, 8 waves, BK=64,
// ring-3 LDS, counted vmcnt(6), exact 1 block/CU fill (256 blocks).
// ---------------------------------------------------------------------------
__global__ __launch_bounds__(512, 2) void gemm2_256x128(
    const u16* __restrict__ A,        // qkv, 16384 x 1536 (lda 1536)
    const u16* __restrict__ Bt,       // Wpt, 512 x 512
    const float* __restrict__ bp,
    const float* __restrict__ amask,
    float* __restrict__ out)          // 16384 x 512 fp32
{
    __shared__ __align__(16) u16 A0[256 * 64];   // 32 KB each
    __shared__ __align__(16) u16 A1[256 * 64];
    __shared__ __align__(16) u16 A2[256 * 64];
    __shared__ __align__(16) u16 B0[128 * 64];   // 16 KB each
    __shared__ __align__(16) u16 B1[128 * 64];
    __shared__ __align__(16) u16 B2[128 * 64];

    const int tid  = threadIdx.x;
    const int wave = tid >> 6;
    const int lane = tid & 63;
    const int quad = lane >> 4;
    const int l16  = lane & 15;
    const int row0 = blockIdx.x * 256;
    const int col0 = blockIdx.y * 128;
    const int wm = (wave >> 1) * 64;   // 4 M-groups
    const int wn = (wave & 1) * 64;    // 2 N-groups

    f32x4 acc[4][4] = {};              // [rg][cg]

    const int rowi = tid >> 3;                       // 0..63
    const int subx = (tid & 7) ^ (rowi & 7);
    const u16* Ag = A  + (size_t)(row0 + rowi) * NQKV + subx * 8;
    const u16* Bg = Bt + (size_t)(col0 + rowi) * 512  + subx * 8;
    const int so = wave * 512;                       // u16, wave-uniform

    const int aoff = (wm + l16) * 64;
    const int boff = (wn + l16) * 64;
    const int sk0 = ((0 + quad) ^ (l16 & 7)) * 8;    // kh=0 (k 0..31)
    const int sk1 = ((4 + quad) ^ (l16 & 7)) * 8;    // kh=1 (k 32..63)

#define SA_(BUF, s, KK) gll16(Ag + (size_t)(s) * 64 * NQKV + (KK), &BUF[(s) * 4096 + so])
#define SB_(BUF, s, KK) gll16(Bg + (size_t)(s) * 64 * 512  + (KK), &BUF[(s) * 4096 + so])

#define BAR2 __builtin_amdgcn_s_barrier()
#define LGK2 do { asm volatile("s_waitcnt lgkmcnt(0)" ::: "memory");          \
                  __builtin_amdgcn_sched_barrier(0); } while (0)

#define PH2(AB, BB, SK, STGS) do {                                            \
    bf16x8 aF[4], bF[4];                                                      \
    _Pragma("unroll")                                                         \
    for (int rg = 0; rg < 4; rg++)                                            \
        aF[rg] = *(const bf16x8*)&AB[aoff + rg * 1024 + (SK)];                \
    _Pragma("unroll")                                                         \
    for (int cg = 0; cg < 4; cg++)                                            \
        bF[cg] = *(const bf16x8*)&BB[boff + cg * 1024 + (SK)];                \
    STGS;                                                                     \
    BAR2; LGK2;                                                               \
    __builtin_amdgcn_s_setprio(1);                                            \
    _Pragma("unroll")                                                         \
    for (int rg = 0; rg < 4; rg++)                                            \
        _Pragma("unroll")                                                     \
        for (int cg = 0; cg < 4; cg++)                                        \
            acc[rg][cg] = __builtin_amdgcn_mfma_f32_16x16x32_bf16(            \
                bF[cg], aF[rg], acc[rg][cg], 0, 0, 0);                        \
    __builtin_amdgcn_s_setprio(0);                                            \
} while (0)

#define TILE2(AB, BB, SA, SB, KK, DO, WK) do {                                \
    PH2(AB, BB, sk0,                                                          \
        if (DO) { SA_(SA, 0, KK); SA_(SA, 1, KK); SA_(SA, 2, KK); });         \
    BAR2;                                                                     \
    PH2(AB, BB, sk1,                                                          \
        if (DO) { SA_(SA, 3, KK); SB_(SB, 0, KK); SB_(SB, 1, KK); });         \
    if ((WK) == 6)      asm volatile("s_waitcnt vmcnt(6)" ::: "memory");      \
    else if ((WK) == 0) asm volatile("s_waitcnt vmcnt(0)" ::: "memory");      \
    BAR2;                                                                     \
} while (0)

    SA_(A0, 0, 0);  SA_(A0, 1, 0);  SA_(A0, 2, 0);  SA_(A0, 3, 0);
    SB_(B0, 0, 0);  SB_(B0, 1, 0);
    SA_(A1, 0, 64); SA_(A1, 1, 64); SA_(A1, 2, 64); SA_(A1, 3, 64);
    SB_(B1, 0, 64); SB_(B1, 1, 64);
    asm volatile("s_waitcnt vmcnt(6)" ::: "memory");
    __builtin_amdgcn_s_barrier();

    TILE2(A0, B0, A2, B2, 128, 1, 6);   // t0 stages t2
    TILE2(A1, B1, A0, B0, 192, 1, 6);   // t1 stages t3
    TILE2(A2, B2, A1, B1, 256, 1, 6);   // t2 stages t4
    TILE2(A0, B0, A2, B2, 320, 1, 6);   // t3 stages t5
    TILE2(A1, B1, A0, B0, 384, 1, 6);   // t4 stages t6
    TILE2(A2, B2, A1, B1, 448, 1, 6);   // t5 stages t7
    TILE2(A0, B0, A1, B1,   0, 0, 0);   // t6 (drain: t7 landed)
    TILE2(A1, B1, A2, B2,   0, 0, -1);  // t7
#undef TILE2
#undef PH2
#undef SA_
#undef SB_
#undef BAR2
#undef LGK2

    #pragma unroll
    for (int rg = 0; rg < 4; rg++) {
        const int row = row0 + wm + rg * 16 + l16;
        const float mval = amask[row];
        #pragma unroll
        for (int cg = 0; cg < 4; cg++) {
            const int colb = col0 + wn + cg * 16 + quad * 4;
            float4 bv = *(const float4*)(bp + colb);
            f32x4 v = acc[rg][cg];
            float4 o = make_float4((v[0] + bv.x) * mval, (v[1] + bv.y) * mval,
                                   (v[2] + bv.z) * mval, (v[3] + bv.w) * mval);
            *(float4*)(out + (size_t)row * 512 + colb) = o;
        }
    }
}

// ---------------------------------------------------------------------------
// R19 attn: 4 lanes per (t,h), each lane owns a 16-wide d-slice.
// R7 budget analysis: attn_win2 is ~70-80 us of unprofiled time — a
// latency/occupancy problem (qf[64] per thread, 4300 VALU ops, 67.5 KB LDS
// -> 2 blocks/CU, ~2-3 waves/SIMD). This version:
//   - 64 t-rows per block, 4 lanes per (t,h): qf[16], o[16], s[15] -> ~60
//     VGPR; 2048 blocks; LDS 19.5 KB -> 8 blocks/CU, up to 32 waves/CU.
//   - QK dot: 16-wide per lane + 2 intra-quad __shfl_xor (lanes t*4+ql).
//   - softmax redundant per quad (15 exps — cheap).
//   - staging idx-linear: coalesced global (consecutive idx = consecutive
//     16B chunks), LDS [j][78] both write (24j+4r)%32 and read (4t)%32
//     patterns hit every bank exactly 8x/wave = conflict-free minimum.
// Rows outside [0,T) get the bias row. Output in place over the q slot
// (only this block's own q rows — no inter-block q reads).
// ---------------------------------------------------------------------------
__global__ __launch_bounds__(256) void attn_win4(u16* __restrict__ qkv,
                                                 const float* __restrict__ bkv)
{
    __shared__ uint4 klds[8 * 78];    // [j][row], row = t - t0 + 7 + w - 7
    __shared__ uint4 vlds[8 * 78];

    const int tid = threadIdx.x;
    const int bid = blockIdx.x;
    const int h  = bid & 7;
    const int b  = (bid >> 3) & 3;
    const int tb = bid >> 5;          // [0,64)
    const int t0 = tb * 64;

    // stage 78 rows x 8 chunks of k and v (624 idx, 3 rounds of 256)
    #pragma unroll
    for (int i = 0; i < 3; i++) {
        int idx = i * 256 + tid;
        if (idx < 624) {
            int row = idx >> 3;
            int j   = idx & 7;
            int tt  = t0 - 7 + row;
            uint4 kc, vc;
            if ((unsigned)tt < (unsigned)T_) {
                const u16* g = qkv + ((size_t)b * T_ + tt) * NQKV + 512 + h * 64 + j * 8;
                kc = *(const uint4*)g;
                vc = *(const uint4*)(g + 512);
            } else {
                union { uint4 u; u16 s[8]; } pk, pv;
                #pragma unroll
                for (int e = 0; e < 8; e++) {
                    pk.s[e] = f2bf(bkv[h * 64 + j * 8 + e]);
                    pv.s[e] = f2bf(bkv[512 + h * 64 + j * 8 + e]);
                }
                kc = pk.u; vc = pv.u;
            }
            klds[j * 78 + row] = kc;
            vlds[j * 78 + row] = vc;
        }
    }
    __syncthreads();

    const int tl = tid >> 2;          // t within block, 0..63
    const int ql = tid & 3;           // d-quarter, 0..3
    u16* qrow = qkv + ((size_t)b * T_ + t0 + tl) * NQKV + h * 64 + ql * 16;

    float qf[16];
    #pragma unroll
    for (int jj = 0; jj < 2; jj++) {
        union { uint4 u; u16 s[8]; } t;
        t.u = *(const uint4*)(qrow + jj * 8);
        #pragma unroll
        for (int e = 0; e < 8; e++) qf[jj * 8 + e] = bf2f(t.s[e]);
    }

    const float scale = 0.042313283f;   // ln(15)/64
    float s[WIN_];
    #pragma unroll
    for (int w = 0; w < WIN_; w++) {
        float acc = 0.f;
        #pragma unroll
        for (int jj = 0; jj < 2; jj++) {
            union { uint4 u; u16 e[8]; } kc;
            kc.u = klds[(ql * 2 + jj) * 78 + tl + w];
            #pragma unroll
            for (int e2 = 0; e2 < 8; e2++)
                acc += qf[jj * 8 + e2] * bf2f(kc.e[e2]);
        }
        // quad reduce (lanes t*4 .. t*4+3)
        acc += __shfl_xor(acc, 1, 64);
        acc += __shfl_xor(acc, 2, 64);
        s[w] = acc * scale;
    }

    float mx = s[0];
    #pragma unroll
    for (int w = 1; w < WIN_; w++) mx = fmaxf(mx, s[w]);
    float sum = 0.f;
    #pragma unroll
    for (int w = 0; w < WIN_; w++) { s[w] = __expf(s[w] - mx); sum += s[w]; }
    const float inv = 1.0f / sum;

    float o[16] = {};
    #pragma unroll
    for (int w = 0; w < WIN_; w++) {
        const float sw = s[w] * inv;
        #pragma unroll
        for (int jj = 0; jj < 2; jj++) {
            union { uint4 u; u16 e[8]; } vc;
            vc.u = vlds[(ql * 2 + jj) * 78 + tl + w];
            #pragma unroll
            for (int e2 = 0; e2 < 8; e2++)
                o[jj * 8 + e2] += sw * bf2f(vc.e[e2]);
        }
    }

    #pragma unroll
    for (int jj = 0; jj < 2; jj++) {
        union { uint4 u; u16 e[8]; } oc;
        #pragma unroll
        for (int e2 = 0; e2 < 8; e2++) oc.e[e2] = f2bf(o[jj * 8 + e2]);
        *(uint4*)(qrow + jj * 8) = oc.u;
    }
}

// ---------------------------------------------------------------------------
// Workspace: 66 MiB total.
//   [0, 1.5Mi)    Wt_qkv (1536x512 bf16)
//   [1.5Mi, 2Mi)  Wpt    (512x512 bf16)
//   [2Mi, 18Mi)   xm     (16384x512 bf16)
//   [18Mi, 66Mi)  qkv    (16384x1536 bf16); q section reused for attn output
// ---------------------------------------------------------------------------
extern "C" void kernel_launch(void* const* d_in, const int* in_sizes, int n_in,
                              void* d_out, int out_size, void* d_ws, size_t ws_size,
                              hipStream_t stream)
{
    const float* x    = (const float*)d_in[0];
    const float* mask = (const float*)d_in[1];
    const float* Wq   = (const float*)d_in[2];
    const float* bq   = (const float*)d_in[3];
    const float* Wkv  = (const float*)d_in[4];
    const float* bkv  = (const float*)d_in[5];
    const float* Wp   = (const float*)d_in[6];
    const float* bp   = (const float*)d_in[7];
    float* out = (float*)d_out;

    char* ws = (char*)d_ws;
    u16* Wt_qkv = (u16*)(ws);
    u16* Wpt    = (u16*)(ws + (size_t)(1536 * 1024));
    u16* xm     = (u16*)(ws + (size_t)(2048 * 1024));
    u16* qkv    = (u16*)(ws + (size_t)(18 * 1024 * 1024));

    pack_weights_t<<<256, 256, 0, stream>>>(Wq, Wkv, Wp, Wt_qkv, Wpt);

    apply_mask<<<(M_ * C_) / (8 * 256), 256, 0, stream>>>(x, mask, xm);

    // GEMM1: proven 128^2 ledger kernel, 2D grid (natural XCD A-affinity)
    dim3 g1(M_ / 128, NQKV / 128);
    gemm_bt_128<false, false><<<g1, 256, 0, stream>>>(
        xm, KDIM, mask, Wt_qkv, bq, bkv, qkv, KDIM, NQKV);

    // attn: 4 lanes per (t,h), 64 t per block -> 2048 blocks
    attn_win4<<<(T_ / 64) * B_ * H_, 256, 0, stream>>>(qkv, bkv);

    // GEMM2: 256x128 phased kernel, grid 64x4 = 256 blocks = exact 1/CU fill
    dim3 g2(M_ / 256, C_ / 128);
    gemm2_256x128<<<g2, 512, 0, stream>>>(qkv, Wpt, bp, mask, out);
}

// Round 9
// 172.616 us; speedup vs baseline: 1.1299x; 1.0063x over previous
//
#include <hip/hip_runtime.h>
#include <hip/hip_bf16.h>

typedef unsigned short u16;

#define B_    4
#define T_    4096
#define C_    512
#define H_    8
#define D_    64
#define WIN_  15
#define PAD_  7
#define M_    (B_*T_)      // 16384 rows
#define NQKV  1536
#define KDIM  512

typedef __bf16 bf16x8 __attribute__((ext_vector_type(8)));
typedef float  f32x4  __attribute__((ext_vector_type(4)));

__device__ __forceinline__ u16 f2bf(float f) {
    union { float f; unsigned int i; } c; c.f = f;
    unsigned int lsb = (c.i >> 16) & 1u;
    c.i += 0x7fffu + lsb;                 // round-to-nearest-even
    return (u16)(c.i >> 16);
}
__device__ __forceinline__ float bf2f(u16 u) {
    union { unsigned int i; float f; } c; c.i = ((unsigned int)u) << 16; return c.f;
}

// BK=32 swizzle for the 128^2 kernel (verified R9).
__device__ __forceinline__ int swz(int row, int sub) {
    return (row * 4 + (sub ^ ((row >> 1) & 3))) * 8;
}

// global->LDS direct DMA, 16B per lane, dest = wave-uniform base + lane*16
__device__ __forceinline__ void gll16(const void* g, void* l) {
    __builtin_amdgcn_global_load_lds(
        (const __attribute__((address_space(1))) void*)g,
        (__attribute__((address_space(3))) void*)l, 16, 0, 0);
}

// ---------------------------------------------------------------------------
// R20 prep = apply_mask (blocks [0,4096)) + pack_weights_t (blocks [4096,4352))
// merged to cut one dispatch from the 5-kernel train (launch train is part of
// the measured iteration; harness overhead is not controllable, ours is).
// Both parts identical to their verified standalone versions.
// ---------------------------------------------------------------------------
__global__ __launch_bounds__(256) void prep(
    const float* __restrict__ x, const float* __restrict__ mask,
    u16* __restrict__ xm,
    const float* __restrict__ Wq, const float* __restrict__ Wkv,
    const float* __restrict__ Wp,
    u16* __restrict__ Wt_qkv, u16* __restrict__ Wpt)
{
    __shared__ float tile[64][65];
    const int bid = blockIdx.x;
    if (bid < 4096) {
        // ---- mask part: xm = bf16(x * mask[row]), 8 elems/thread ----
        int idx = bid * 256 + threadIdx.x;
        int e0 = idx * 8;
        float mval = mask[e0 >> 9];
        float4 a = *(const float4*)(x + e0);
        float4 b = *(const float4*)(x + e0 + 4);
        union { uint4 u; u16 s[8]; } o;
        o.s[0] = f2bf(a.x * mval); o.s[1] = f2bf(a.y * mval);
        o.s[2] = f2bf(a.z * mval); o.s[3] = f2bf(a.w * mval);
        o.s[4] = f2bf(b.x * mval); o.s[5] = f2bf(b.y * mval);
        o.s[6] = f2bf(b.z * mval); o.s[7] = f2bf(b.w * mval);
        *(uint4*)(xm + e0) = o.u;
        return;
    }
    // ---- pack part: coalesced 64x64 LDS transpose (verified R15) ----
    const int pb = bid - 4096;
    const float* src; int srcld; u16* dst; int n0, k0;
    if (pb < 192) {             // Wt_qkv: n0 in [0,1536), k0 in [0,512)
        n0 = (pb % 24) * 64; k0 = (pb / 24) * 64;
        dst = Wt_qkv;
        if (n0 < 512) { src = Wq + n0;          srcld = 512;  }
        else          { src = Wkv + (n0 - 512); srcld = 1024; }
    } else {                    // Wpt
        const int b2 = pb - 192;
        n0 = (b2 % 8) * 64; k0 = (b2 / 8) * 64;
        dst = Wpt; src = Wp + n0; srcld = 512;
    }
    const int tr = threadIdx.x >> 6;   // 0..3
    const int tc = threadIdx.x & 63;
    #pragma unroll
    for (int p = 0; p < 16; p++) {
        const int kk = p * 4 + tr;
        tile[kk][tc] = src[(size_t)(k0 + kk) * srcld + tc];
    }
    __syncthreads();
    #pragma unroll
    for (int p = 0; p < 16; p++) {
        const int nn = p * 4 + tr;
        dst[(size_t)(n0 + nn) * 512 + k0 + tc] = f2bf(tile[tc][nn]);
    }
}

// ---------------------------------------------------------------------------
// GEMM1 (R16, proven 45.3 us): 128x128, 4 waves, 2D grid, triple-buffer
// counted-vmcnt ledger, one s_barrier per K-step. Natural round-robin with
// gridDim.x=128 (%8==0) pins row-block r to XCD r%8 -> A-panel L2 affinity.
// ---------------------------------------------------------------------------
template<bool USE_MASK, bool OUT_F32>
__global__ __launch_bounds__(256) void gemm_bt_128(
    const u16* __restrict__ A, int lda,
    const float* __restrict__ amask,
    const u16* __restrict__ Bt,
    const float* __restrict__ bias0, const float* __restrict__ bias1,
    void* __restrict__ Cc,
    int K, int N)
{
    __shared__ __align__(16) u16 As0[128 * 32];
    __shared__ __align__(16) u16 As1[128 * 32];
    __shared__ __align__(16) u16 As2[128 * 32];
    __shared__ __align__(16) u16 Bs0[128 * 32];
    __shared__ __align__(16) u16 Bs1[128 * 32];
    __shared__ __align__(16) u16 Bs2[128 * 32];

    const int tid  = threadIdx.x;
    const int wave = tid >> 6;
    const int lane = tid & 63;
    const int row0 = blockIdx.x * 128;
    const int col0 = blockIdx.y * 128;

    const int wm = (wave >> 1) * 64;
    const int wn = (wave & 1) * 64;

    f32x4 acc[4][4] = {};

    const int quad = lane >> 4;
    const int l16  = lane & 15;

    const int cA = wave * 128 + lane;
    const int cB = cA + 64;
    const int rA = cA >> 2, sA = (cA & 3) ^ ((rA >> 1) & 3);
    const int rB = cB >> 2, sB = (cB & 3) ^ ((rB >> 1) & 3);
    const u16* Ag0 = A  + (size_t)(row0 + rA) * lda + sA * 8;
    const u16* Ag1 = A  + (size_t)(row0 + rB) * lda + sB * 8;
    const u16* Bg0 = Bt + (size_t)(col0 + rA) * K   + sA * 8;
    const u16* Bg1 = Bt + (size_t)(col0 + rB) * K   + sB * 8;
    const int ldsOff0 = wave * 1024;
    const int ldsOff1 = wave * 1024 + 512;

#define FR(BUF, R) (*(const bf16x8*)&BUF[swz((R) + l16, quad)])

#define STAGE(SA, SB, KST)                         \
    do {                                           \
        gll16(Ag0 + (KST), &SA[ldsOff0]);          \
        gll16(Ag1 + (KST), &SA[ldsOff1]);          \
        gll16(Bg0 + (KST), &SB[ldsOff0]);          \
        gll16(Bg1 + (KST), &SB[ldsOff1]);          \
    } while (0)

#define TILE(RA, RB, SA, SB, KST, MODE)                                      \
    do {                                                                     \
        if ((MODE) == 1) STAGE(SA, SB, KST);                                 \
        bf16x8 a[4], b[4];                                                   \
        _Pragma("unroll")                                                    \
        for (int i = 0; i < 4; i++) {                                        \
            a[i] = FR(RA, wm + i * 16);                                      \
            b[i] = FR(RB, wn + i * 16);                                      \
        }                                                                    \
        __builtin_amdgcn_s_setprio(1);                                       \
        _Pragma("unroll")                                                    \
        for (int ci = 0; ci < 4; ci++)                                       \
            _Pragma("unroll")                                                \
            for (int ri = 0; ri < 4; ri++)                                   \
                acc[ci][ri] = __builtin_amdgcn_mfma_f32_16x16x32_bf16(       \
                    b[ci], a[ri], acc[ci][ri], 0, 0, 0);                     \
        __builtin_amdgcn_s_setprio(0);                                       \
        if ((MODE) == 1)      asm volatile("s_waitcnt vmcnt(4)" ::: "memory"); \
        else if ((MODE) == 0) asm volatile("s_waitcnt vmcnt(0)" ::: "memory"); \
        if ((MODE) >= 0) __builtin_amdgcn_s_barrier();                       \
    } while (0)

    STAGE(As0, Bs0, 0);
    STAGE(As1, Bs1, 32);
    asm volatile("s_waitcnt vmcnt(4)" ::: "memory");
    __builtin_amdgcn_s_barrier();

    TILE(As0, Bs0, As2, Bs2,  64, 1);
    TILE(As1, Bs1, As0, Bs0,  96, 1);
    TILE(As2, Bs2, As1, Bs1, 128, 1);
    TILE(As0, Bs0, As2, Bs2, 160, 1);
    TILE(As1, Bs1, As0, Bs0, 192, 1);
    TILE(As2, Bs2, As1, Bs1, 224, 1);
    TILE(As0, Bs0, As2, Bs2, 256, 1);
    TILE(As1, Bs1, As0, Bs0, 288, 1);
    TILE(As2, Bs2, As1, Bs1, 320, 1);
    TILE(As0, Bs0, As2, Bs2, 352, 1);
    TILE(As1, Bs1, As0, Bs0, 384, 1);
    TILE(As2, Bs2, As1, Bs1, 416, 1);
    TILE(As0, Bs0, As2, Bs2, 448, 1);
    TILE(As1, Bs1, As0, Bs0, 480, 1);
    TILE(As2, Bs2, As0, Bs0,   0, 0);
    TILE(As0, Bs0, As1, Bs1,   0, -1);
#undef TILE
#undef STAGE
#undef FR

    #pragma unroll
    for (int ri = 0; ri < 4; ri++) {
        const int row = row0 + wm + ri * 16 + l16;
        float mval = 1.f;
        if (USE_MASK) mval = amask[row];
        #pragma unroll
        for (int ci = 0; ci < 4; ci++) {
            const int colb = col0 + wn + ci * 16 + quad * 4;
            float4 bv = (colb < 512) ? *(const float4*)(bias0 + colb)
                                     : *(const float4*)(bias1 + colb - 512);
            f32x4 v = acc[ci][ri];
            float v0 = v[0] + bv.x, v1 = v[1] + bv.y,
                  v2 = v[2] + bv.z, v3 = v[3] + bv.w;
            if (USE_MASK) { v0 *= mval; v1 *= mval; v2 *= mval; v3 *= mval; }
            if (OUT_F32) {
                float4 o = make_float4(v0, v1, v2, v3);
                *(float4*)((float*)Cc + (size_t)row * N + colb) = o;
            } else {
                union { uint2 u; u16 s[4]; } o;
                o.s[0] = f2bf(v0); o.s[1] = f2bf(v1);
                o.s[2] = f2bf(v2); o.s[3] = f2bf(v3);
                *(uint2*)((u16*)Cc + (size_t)row * N + colb) = o.u;
            }
        }
    }
}

// ---------------------------------------------------------------------------
// R20 GEMM2: 256x128 tile, 8 waves (4Mx2N, wave=64x64), BK=64, ring-3 LDS,
// ONE barrier per K-tile (was 4 in R18 -> 32 barriers at 1 block/CU with
// zero co-resident cover = convoy stalls). Sync proof:
//   - RAW (stage->read): end of tile t has per-wave vmcnt(6) (6 gll/tile ->
//     only t+2's 6 outstanding => t+1's landed) BEFORE the barrier; barrier
//     publishes landing across waves. Tile t's data was verified at end of
//     t-1 by every wave.
//   - WAR (read->re-stage): buf staged at tile t was read at t-1; those
//     ds_reads completed (lgkmcnt(0) precedes MFMA precedes barrier) before
//     t-1's closing barrier; stages issue after it.
// Per tile: {16 ds_read | 6 gll} -> lgkm(0)+sched_barrier -> setprio(1) ->
// 32 MFMA -> setprio(0) -> vmcnt(6) -> s_barrier.  8 barriers total.
// Grid 64x4 = 256 blocks = exact 1 block/CU fill.
// ---------------------------------------------------------------------------
__global__ __launch_bounds__(512, 2) void gemm2_256x128(
    const u16* __restrict__ A,        // qkv, 16384 x 1536 (reads cols 0..511)
    const u16* __restrict__ Bt,       // Wpt, 512 x 512
    const float* __restrict__ bp,
    const float* __restrict__ amask,
    float* __restrict__ out)          // 16384 x 512 fp32
{
    __shared__ __align__(16) u16 A0[256 * 64];   // 32 KB each
    __shared__ __align__(16) u16 A1[256 * 64];
    __shared__ __align__(16) u16 A2[256 * 64];
    __shared__ __align__(16) u16 B0[128 * 64];   // 16 KB each
    __shared__ __align__(16) u16 B1[128 * 64];
    __shared__ __align__(16) u16 B2[128 * 64];

    const int tid  = threadIdx.x;
    const int wave = tid >> 6;
    const int lane = tid & 63;
    const int quad = lane >> 4;
    const int l16  = lane & 15;
    const int row0 = blockIdx.x * 256;
    const int col0 = blockIdx.y * 128;
    const int wm = (wave >> 1) * 64;   // 4 M-groups
    const int wn = (wave & 1) * 64;    // 2 N-groups

    f32x4 acc[4][4] = {};              // [rg][cg]

    // staging: stage s covers tile rows s*64..s*64+63; lane chunk = s*512+tid
    // -> row = s*64 + (tid>>3), slot tid&7 holds src sub (tid&7)^(row&7).
    const int rowi = tid >> 3;                       // 0..63
    const int subx = (tid & 7) ^ (rowi & 7);
    const u16* Ag = A  + (size_t)(row0 + rowi) * NQKV + subx * 8;
    const u16* Bg = Bt + (size_t)(col0 + rowi) * 512  + subx * 8;
    const int so = wave * 512;                       // u16, wave-uniform

    const int aoff = (wm + l16) * 64;
    const int boff = (wn + l16) * 64;
    const int sk0 = ((0 + quad) ^ (l16 & 7)) * 8;    // kh=0 (k 0..31)
    const int sk1 = ((4 + quad) ^ (l16 & 7)) * 8;    // kh=1 (k 32..63)

#define SA_(BUF, s, KK) gll16(Ag + (size_t)(s) * 64 * NQKV + (KK), &BUF[(s) * 4096 + so])
#define SB_(BUF, s, KK) gll16(Bg + (size_t)(s) * 64 * 512  + (KK), &BUF[(s) * 4096 + so])

// one K-tile, single-barrier. DO: stage t+2 at k-offset KK. WK: 6/0/-1.
#define TILE2(AB, BB, SA, SB, KK, DO, WK) do {                                \
    bf16x8 aF0[4], aF1[4], bF0[4], bF1[4];                                    \
    _Pragma("unroll")                                                         \
    for (int rg = 0; rg < 4; rg++) {                                          \
        aF0[rg] = *(const bf16x8*)&AB[aoff + rg * 1024 + sk0];                \
        aF1[rg] = *(const bf16x8*)&AB[aoff + rg * 1024 + sk1];                \
    }                                                                         \
    _Pragma("unroll")                                                         \
    for (int cg = 0; cg < 4; cg++) {                                          \
        bF0[cg] = *(const bf16x8*)&BB[boff + cg * 1024 + sk0];                \
        bF1[cg] = *(const bf16x8*)&BB[boff + cg * 1024 + sk1];                \
    }                                                                         \
    if (DO) { SA_(SA, 0, KK); SA_(SA, 1, KK); SA_(SA, 2, KK); SA_(SA, 3, KK); \
              SB_(SB, 0, KK); SB_(SB, 1, KK); }                               \
    asm volatile("s_waitcnt lgkmcnt(0)" ::: "memory");                        \
    __builtin_amdgcn_sched_barrier(0);                                        \
    __builtin_amdgcn_s_setprio(1);                                            \
    _Pragma("unroll")                                                         \
    for (int rg = 0; rg < 4; rg++)                                            \
        _Pragma("unroll")                                                     \
        for (int cg = 0; cg < 4; cg++) {                                      \
            acc[rg][cg] = __builtin_amdgcn_mfma_f32_16x16x32_bf16(            \
                bF0[cg], aF0[rg], acc[rg][cg], 0, 0, 0);                      \
            acc[rg][cg] = __builtin_amdgcn_mfma_f32_16x16x32_bf16(            \
                bF1[cg], aF1[rg], acc[rg][cg], 0, 0, 0);                      \
        }                                                                     \
    __builtin_amdgcn_s_setprio(0);                                            \
    if ((WK) == 6)      asm volatile("s_waitcnt vmcnt(6)" ::: "memory");      \
    else if ((WK) == 0) asm volatile("s_waitcnt vmcnt(0)" ::: "memory");      \
    if ((WK) >= 0) __builtin_amdgcn_s_barrier();                              \
} while (0)

    // prologue: stage tiles 0,1 (12 gll/wave); vmcnt(6) -> tile 0 landed
    SA_(A0, 0, 0);  SA_(A0, 1, 0);  SA_(A0, 2, 0);  SA_(A0, 3, 0);
    SB_(B0, 0, 0);  SB_(B0, 1, 0);
    SA_(A1, 0, 64); SA_(A1, 1, 64); SA_(A1, 2, 64); SA_(A1, 3, 64);
    SB_(B1, 0, 64); SB_(B1, 1, 64);
    asm volatile("s_waitcnt vmcnt(6)" ::: "memory");
    __builtin_amdgcn_s_barrier();

    // 8 K-tiles (K=512, BK=64), ring-3: read buf t%3, stage t+2 -> (t+2)%3
    TILE2(A0, B0, A2, B2, 128, 1, 6);   // t0 stages t2
    TILE2(A1, B1, A0, B0, 192, 1, 6);   // t1 stages t3
    TILE2(A2, B2, A1, B1, 256, 1, 6);   // t2 stages t4
    TILE2(A0, B0, A2, B2, 320, 1, 6);   // t3 stages t5
    TILE2(A1, B1, A0, B0, 384, 1, 6);   // t4 stages t6
    TILE2(A2, B2, A1, B1, 448, 1, 6);   // t5 stages t7
    TILE2(A0, B0, A1, B1,   0, 0, 0);   // t6 (drain: t7 landed)
    TILE2(A1, B1, A2, B2,   0, 0, -1);  // t7
#undef TILE2
#undef SA_
#undef SB_

    // epilogue: bias + row mask, fp32 float4 stores (register-direct)
    #pragma unroll
    for (int rg = 0; rg < 4; rg++) {
        const int row = row0 + wm + rg * 16 + l16;
        const float mval = amask[row];
        #pragma unroll
        for (int cg = 0; cg < 4; cg++) {
            const int colb = col0 + wn + cg * 16 + quad * 4;
            float4 bv = *(const float4*)(bp + colb);
            f32x4 v = acc[rg][cg];
            float4 o = make_float4((v[0] + bv.x) * mval, (v[1] + bv.y) * mval,
                                   (v[2] + bv.z) * mval, (v[3] + bv.w) * mval);
            *(float4*)(out + (size_t)row * 512 + colb) = o;
        }
    }
}

// ---------------------------------------------------------------------------
// R19 attn (proven +14 us): 4 lanes per (t,h), 64 t-rows/block, qf[16]/o[16]
// per lane, intra-quad shfl_xor QK reduce, conflict-free [j][78] LDS.
// ---------------------------------------------------------------------------
__global__ __launch_bounds__(256) void attn_win4(u16* __restrict__ qkv,
                                                 const float* __restrict__ bkv)
{
    __shared__ uint4 klds[8 * 78];    // [j][row]
    __shared__ uint4 vlds[8 * 78];

    const int tid = threadIdx.x;
    const int bid = blockIdx.x;
    const int h  = bid & 7;
    const int b  = (bid >> 3) & 3;
    const int tb = bid >> 5;          // [0,64)
    const int t0 = tb * 64;

    #pragma unroll
    for (int i = 0; i < 3; i++) {
        int idx = i * 256 + tid;
        if (idx < 624) {
            int row = idx >> 3;
            int j   = idx & 7;
            int tt  = t0 - 7 + row;
            uint4 kc, vc;
            if ((unsigned)tt < (unsigned)T_) {
                const u16* g = qkv + ((size_t)b * T_ + tt) * NQKV + 512 + h * 64 + j * 8;
                kc = *(const uint4*)g;
                vc = *(const uint4*)(g + 512);
            } else {
                union { uint4 u; u16 s[8]; } pk, pv;
                #pragma unroll
                for (int e = 0; e < 8; e++) {
                    pk.s[e] = f2bf(bkv[h * 64 + j * 8 + e]);
                    pv.s[e] = f2bf(bkv[512 + h * 64 + j * 8 + e]);
                }
                kc = pk.u; vc = pv.u;
            }
            klds[j * 78 + row] = kc;
            vlds[j * 78 + row] = vc;
        }
    }
    __syncthreads();

    const int tl = tid >> 2;          // t within block, 0..63
    const int ql = tid & 3;           // d-quarter, 0..3
    u16* qrow = qkv + ((size_t)b * T_ + t0 + tl) * NQKV + h * 64 + ql * 16;

    float qf[16];
    #pragma unroll
    for (int jj = 0; jj < 2; jj++) {
        union { uint4 u; u16 s[8]; } t;
        t.u = *(const uint4*)(qrow + jj * 8);
        #pragma unroll
        for (int e = 0; e < 8; e++) qf[jj * 8 + e] = bf2f(t.s[e]);
    }

    const float scale = 0.042313283f;   // ln(15)/64
    float s[WIN_];
    #pragma unroll
    for (int w = 0; w < WIN_; w++) {
        float acc = 0.f;
        #pragma unroll
        for (int jj = 0; jj < 2; jj++) {
            union { uint4 u; u16 e[8]; } kc;
            kc.u = klds[(ql * 2 + jj) * 78 + tl + w];
            #pragma unroll
            for (int e2 = 0; e2 < 8; e2++)
                acc += qf[jj * 8 + e2] * bf2f(kc.e[e2]);
        }
        acc += __shfl_xor(acc, 1, 64);
        acc += __shfl_xor(acc, 2, 64);
        s[w] = acc * scale;
    }

    float mx = s[0];
    #pragma unroll
    for (int w = 1; w < WIN_; w++) mx = fmaxf(mx, s[w]);
    float sum = 0.f;
    #pragma unroll
    for (int w = 0; w < WIN_; w++) { s[w] = __expf(s[w] - mx); sum += s[w]; }
    const float inv = 1.0f / sum;

    float o[16] = {};
    #pragma unroll
    for (int w = 0; w < WIN_; w++) {
        const float sw = s[w] * inv;
        #pragma unroll
        for (int jj = 0; jj < 2; jj++) {
            union { uint4 u; u16 e[8]; } vc;
            vc.u = vlds[(ql * 2 + jj) * 78 + tl + w];
            #pragma unroll
            for (int e2 = 0; e2 < 8; e2++)
                o[jj * 8 + e2] += sw * bf2f(vc.e[e2]);
        }
    }

    #pragma unroll
    for (int jj = 0; jj < 2; jj++) {
        union { uint4 u; u16 e[8]; } oc;
        #pragma unroll
        for (int e2 = 0; e2 < 8; e2++) oc.e[e2] = f2bf(o[jj * 8 + e2]);
        *(uint4*)(qrow + jj * 8) = oc.u;
    }
}

// ---------------------------------------------------------------------------
// Workspace: 66 MiB total.
//   [0, 1.5Mi)    Wt_qkv (1536x512 bf16)
//   [1.5Mi, 2Mi)  Wpt    (512x512 bf16)
//   [2Mi, 18Mi)   xm     (16384x512 bf16)
//   [18Mi, 66Mi)  qkv    (16384x1536 bf16); q section reused for attn output
// ---------------------------------------------------------------------------
extern "C" void kernel_launch(void* const* d_in, const int* in_sizes, int n_in,
                              void* d_out, int out_size, void* d_ws, size_t ws_size,
                              hipStream_t stream)
{
    const float* x    = (const float*)d_in[0];
    const float* mask = (const float*)d_in[1];
    const float* Wq   = (const float*)d_in[2];
    const float* bq   = (const float*)d_in[3];
    const float* Wkv  = (const float*)d_in[4];
    const float* bkv  = (const float*)d_in[5];
    const float* Wp   = (const float*)d_in[6];
    const float* bp   = (const float*)d_in[7];
    float* out = (float*)d_out;

    char* ws = (char*)d_ws;
    u16* Wt_qkv = (u16*)(ws);
    u16* Wpt    = (u16*)(ws + (size_t)(1536 * 1024));
    u16* xm     = (u16*)(ws + (size_t)(2048 * 1024));
    u16* qkv    = (u16*)(ws + (size_t)(18 * 1024 * 1024));

    // prep: mask (4096 blocks) + weight pack (256 blocks) in one dispatch
    prep<<<4352, 256, 0, stream>>>(x, mask, xm, Wq, Wkv, Wp, Wt_qkv, Wpt);

    // GEMM1: proven 128^2 ledger kernel, 2D grid (natural XCD A-affinity)
    dim3 g1(M_ / 128, NQKV / 128);
    gemm_bt_128<false, false><<<g1, 256, 0, stream>>>(
        xm, KDIM, mask, Wt_qkv, bq, bkv, qkv, KDIM, NQKV);

    // attn: 4 lanes per (t,h), 64 t per block -> 2048 blocks
    attn_win4<<<(T_ / 64) * B_ * H_, 256, 0, stream>>>(qkv, bkv);

    // GEMM2: 256x128 single-barrier-per-tile kernel, 256 blocks = 1/CU
    dim3 g2(M_ / 256, C_ / 128);
    gemm2_256x128<<<g2, 512, 0, stream>>>(qkv, Wpt, bp, mask, out);
}